// Round 15
// baseline (1110.817 us; speedup 1.0000x reference)
//
#include <hip/hip_runtime.h>
#include <math.h>

#define NLAY 8
#define BB 4
#define LL 512
#define DDIM 512
#define HH 16
#define KHD 32
#define FFD 2048
#define MMD 512
#define NDB 14
#define QKS 1536
#define SCALEF 0.17677669529663687f

typedef unsigned short u16;
typedef unsigned int u32;
typedef __attribute__((ext_vector_type(8))) short bf16x8;
typedef __attribute__((ext_vector_type(4))) float f32x4;
typedef __attribute__((ext_vector_type(4))) u32 u32x4;

__device__ __forceinline__ u16 f2bf(float f) {
  unsigned u = __builtin_bit_cast(unsigned, f);
  u = (u + 0x7fffu + ((u >> 16) & 1u)) >> 16;
  return (u16)u;
}
__device__ __forceinline__ float bf2f(u16 v) {
  unsigned u = ((unsigned)v) << 16;
  return __builtin_bit_cast(float, u);
}
__device__ __forceinline__ u32 cvt_pk_bf16(float lo, float hi) {
  u32 r;
  asm("v_cvt_pk_bf16_f32 %0, %1, %2" : "=v"(r) : "v"(lo), "v"(hi));
  return r;
}
__device__ __forceinline__ float wredSum(float v) {
#pragma unroll
  for (int o = 32; o > 0; o >>= 1) v += __shfl_down(v, o);
  return v;
}
__device__ __forceinline__ void gload_lds16(const u16* g, u16* l) {
  __builtin_amdgcn_global_load_lds((const __attribute__((address_space(1))) void*)g,
                                   (__attribute__((address_space(3))) void*)l, 16, 0, 0);
}

// ---------------- bucketize -> uint8, [b][l][x] layout ----------------
__global__ void bucketize_kernel(const float* __restrict__ dist, unsigned char* __restrict__ didx, int n) {
  int i = blockIdx.x * 256 + threadIdx.x;
  if (i >= n) return;
  float4 v = ((const float4*)dist)[i];
  float vv[4] = {v.x, v.y, v.z, v.w};
  unsigned char o[4];
#pragma unroll
  for (int j = 0; j < 4; ++j) {
    int c = 0;
#pragma unroll
    for (int s = 1; s <= NDB; ++s) c += (10.0f * (float)s < vv[j]) ? 1 : 0;
    o[j] = (unsigned char)(c > (NDB - 1) ? (NDB - 1) : c);
  }
  *(uchar4*)(didx + i * 4) = *(uchar4*)o;
}

// ---------------- h = cell_emb[cell_types] (f32 + bf16) ----------------
__global__ void embed_kernel(const int* __restrict__ ct, const float* __restrict__ emb,
                             float* __restrict__ h, u16* __restrict__ hbf, int n) {
  int i = blockIdx.x * 256 + threadIdx.x;
  if (i >= n) return;
  int bl = i >> 9, d = i & 511;
  float v = emb[ct[bl] * DDIM + d];
  h[i] = v;
  hbf[i] = f2bf(v);
}

// ---------------- Vsum, EkrS ----------------
__global__ void prep_kernel(const float* __restrict__ Vqk, const float* __restrict__ Vqr,
                            const float* __restrict__ Vkr, const float* __restrict__ Kkr,
                            float* __restrict__ Vsum, float* __restrict__ EkrS) {
  int tid = threadIdx.x;
  if (tid < NDB * KHD) Vsum[tid] = Vqk[tid] + Vqr[tid] + Vkr[tid];
  if (tid < NDB) {
    float s = 0.f;
    for (int kk = 0; kk < KHD; ++kk) s += Kkr[tid * KHD + kk];
    EkrS[tid] = s;
  }
}

// ---------------- packed qkv bias [NLAY][1536] ----------------
__global__ void biaspack_kernel(const float* __restrict__ bq, const float* __restrict__ bk,
                                const float* __restrict__ bv, float* __restrict__ bqkv) {
  int i = blockIdx.x * 256 + threadIdx.x;
  if (i >= NLAY * QKS) return;
  int lay = i / QKS, c = i % QKS;
  float v;
  if (c < 512) v = bq[lay * DDIM + c];
  else if (c < 1024) v = bk[lay * DDIM + c - 512];
  else v = bv[lay * DDIM + c - 1024];
  bqkv[i] = v;
}

// ---------------- weight transpose+convert ----------------
__device__ __forceinline__ void wtconv_tile(const float* __restrict__ src, u16* __restrict__ dst,
                                            int K, int N, int tn, int tk) {
  __shared__ float tl[64][65];
  const int t = threadIdx.x;
#pragma unroll
  for (int p = 0; p < 4; ++p) {
    int k = tk * 64 + p * 16 + (t >> 4);
    int n = tn * 64 + (t & 15) * 4;
    float4 v = *(const float4*)(src + (size_t)k * N + n);
    tl[(t & 15) * 4 + 0][p * 16 + (t >> 4)] = v.x;
    tl[(t & 15) * 4 + 1][p * 16 + (t >> 4)] = v.y;
    tl[(t & 15) * 4 + 2][p * 16 + (t >> 4)] = v.z;
    tl[(t & 15) * 4 + 3][p * 16 + (t >> 4)] = v.w;
  }
  __syncthreads();
  int n = t >> 2, cc = t & 3;
  u16 o[16];
#pragma unroll
  for (int e = 0; e < 16; ++e) o[e] = f2bf(tl[n][cc * 16 + e]);
  u16* dp = dst + (size_t)(tn * 64 + n) * K + tk * 64 + cc * 16;
  *(uint4*)(dp) = *(uint4*)&o[0];
  *(uint4*)(dp + 8) = *(uint4*)&o[8];
}

__global__ __launch_bounds__(256) void wconv_layer(
    const float* __restrict__ Wq, const float* __restrict__ Wk, const float* __restrict__ Wv,
    const float* __restrict__ Wo, const float* __restrict__ W1, const float* __restrict__ W2,
    u16* __restrict__ Wqkvt, u16* __restrict__ Wot, u16* __restrict__ W1t, u16* __restrict__ W2t) {
  int b = blockIdx.x;
  if (b < 64) { wtconv_tile(Wq, Wqkvt, 512, 512, b >> 3, b & 7); return; }
  if (b < 128) { b -= 64; wtconv_tile(Wk, Wqkvt + 512 * 512, 512, 512, b >> 3, b & 7); return; }
  if (b < 192) { b -= 128; wtconv_tile(Wv, Wqkvt + 1024 * 512, 512, 512, b >> 3, b & 7); return; }
  if (b < 256) { b -= 192; wtconv_tile(Wo, Wot, 512, 512, b >> 3, b & 7); return; }
  if (b < 512) { b -= 256; wtconv_tile(W1, W1t, 512, FFD, b >> 3, b & 7); return; }
  b -= 512; wtconv_tile(W2, W2t, FFD, 512, b >> 5, b & 31);
}

// ---------------- bf16 MFMA GEMM: 32x64 tile, BK=64, 4 waves (2x2), XCD y-chunked swizzle ----------------
__global__ __launch_bounds__(256) void gemm_bf16(
    const u16* __restrict__ A, const u16* __restrict__ Bt, const float* __restrict__ bias,
    float* __restrict__ Cf, u16* __restrict__ Cb,
    int M, int N, int K, int act, int scaleLT) {
  __shared__ u16 As[32 * 64];
  __shared__ u16 Bs[64 * 64];
  const int tid = threadIdx.x, w = tid >> 6, lane = tid & 63;
  const int lr = lane & 15, lg = lane >> 4;
  const int wr = w >> 1, wc = w & 1;
  const int gx = N >> 6;
  const int bi = blockIdx.x;
  const int xcd = bi & 7, rr = bi >> 3;
  const int y = xcd * 8 + rr / gx, x = rr % gx;
  const int row0 = y * 32, col0 = x * 64;
  const int srow = lane >> 3;
  const int aoff = ((lane & 7) ^ srow) * 8;
  const f32x4 z4 = {0.f, 0.f, 0.f, 0.f};
  f32x4 acc[2] = {z4, z4};

  for (int k0 = 0; k0 < K; k0 += 64) {
    gload_lds16(A + (size_t)(row0 + w * 8 + srow) * K + k0 + aoff, As + (w * 8) * 64);
#pragma unroll
    for (int i = 0; i < 2; ++i)
      gload_lds16(Bt + (size_t)(col0 + w * 16 + i * 8 + srow) * K + k0 + aoff,
                  Bs + (w * 16 + i * 8) * 64);
    __syncthreads();
#pragma unroll
    for (int kh = 0; kh < 2; ++kh) {
      bf16x8 a, b[2];
      {
        int r = wr * 16 + lr;
        a = *(const bf16x8*)(As + r * 64 + (((kh * 4 + lg) ^ (r & 7)) << 3));
      }
#pragma unroll
      for (int ni = 0; ni < 2; ++ni) {
        int r = wc * 32 + ni * 16 + lr;
        b[ni] = *(const bf16x8*)(Bs + r * 64 + (((kh * 4 + lg) ^ (r & 7)) << 3));
      }
#pragma unroll
      for (int ni = 0; ni < 2; ++ni)
        acc[ni] = __builtin_amdgcn_mfma_f32_16x16x32_bf16(a, b[ni], acc[ni], 0, 0, 0);
    }
    __syncthreads();
  }
  {
    int r = row0 + wr * 16 + lg * 4;
#pragma unroll
    for (int ni = 0; ni < 2; ++ni) {
      int c = col0 + wc * 32 + ni * 16 + lr;
      float bs = bias[c];
      float sc = (c < scaleLT) ? SCALEF : 1.0f;
#pragma unroll
      for (int j = 0; j < 4; ++j) {
        float v = acc[ni][j] + bs;
        if (act == 1) v = 0.5f * v * (1.0f + erff(v * 0.70710678118654752f));
        size_t idx = (size_t)(r + j) * N + c;
        if (Cf) Cf[idx] = v;
        if (Cb) Cb[idx] = f2bf(v * sc);
      }
    }
  }
}

// ---------------- merged rel projections: qE2 (f32) + kEbf (bf16 [bhl][16]) ----------------
__global__ void proj_qk_kernel(const u16* __restrict__ qkv, const float* __restrict__ Kqk,
                               const float* __restrict__ Kqr, const float* __restrict__ ekrs,
                               float* __restrict__ qE2, u16* __restrict__ kEbf) {
  int idx = blockIdx.x * 256 + threadIdx.x;
  if (idx >= BB * HH * LL * NDB) return;
  int d = idx % NDB;
  int rest = idx / NDB;
  int l = rest & (LL - 1);
  int bh = rest >> 9;
  int h = bh & (HH - 1);
  int b = bh >> 4;
  const u16* qr_ = qkv + ((size_t)(b * LL + l)) * QKS + h * KHD;
  const u16* kr_ = qr_ + 512;
  const float* kq = Kqk + d * KHD;
  const float* kk2 = Kqr + d * KHD;
  float sq = 0.f, sk = 0.f;
#pragma unroll
  for (int kk = 0; kk < KHD; ++kk) {
    sq += bf2f(qr_[kk]) * kq[kk];
    sk += bf2f(kr_[kk]) * kk2[kk];
  }
  qE2[idx] = sq;  // q pre-scaled by SCALEF in QKV epilogue
  kEbf[(size_t)rest * 16 + d] = f2bf(sk * SCALEF + SCALEF * ekrs[d]);
}

// ---------------- v -> vt [b,h,kh,x] bf16 ----------------
__global__ __launch_bounds__(256) void vtrans_kernel(const u16* __restrict__ qkv, u16* __restrict__ vt) {
  const int h = blockIdx.x, b = blockIdx.y, tid = threadIdx.x;
  __shared__ u16 tile[KHD][520];
  for (int it = 0; it < 64; ++it) {
    int idx = it * 256 + tid;
    int x = idx >> 5, kh = idx & 31;
    tile[kh][x] = qkv[((size_t)(b * LL) + x) * QKS + 1024 + h * KHD + kh];
  }
  __syncthreads();
  int r = tid >> 3, seg = tid & 7;
  uint4* dst = (uint4*)(vt + ((size_t)(b * HH + h) * KHD + r) * LL);
  const uint4* src = (const uint4*)(&tile[r][0]);
#pragma unroll
  for (int j = 0; j < 8; ++j) dst[seg + j * 8] = src[seg + j * 8];
}

// ---------------- FUSED attention: batched loads (sched_barrier) + in-register P -> PV ----------------
// Round-13 discipline (all VMEM issued before compute, fence blocks sinking) extended to V:
// 20 loads in flight (8 K + 4 didx + 8 V). P never leaves registers (cvt_pk -> PV A-frag,
// layout verified in rounds 7-8). Kills the 33 MB E write + 33 MB E read per layer.
// kv-split merge: o partials via osh LDS atomics (once per block, off critical path).
__global__ __launch_bounds__(256) void attn_fused_kernel(
    const u16* __restrict__ qkv, const u16* __restrict__ vtbf,
    const float* __restrict__ qE2, const u16* __restrict__ kEbf,
    const unsigned char* __restrict__ didx, const float* __restrict__ Vsum,
    u16* __restrict__ z) {
  const int i = blockIdx.x;
  const int j = i >> 3;
  const int g = (i & 7) * 8 + (j >> 5);   // 8 (b,h)-groups per XCD
  const int qr = j & 31;
  const int h = g & 15, b = g >> 4;
  const int tid = threadIdx.x, lane = tid & 63, w = tid >> 6;
  const int lr = lane & 15, lg = lane >> 4;
  const int row0 = qr * 16;

  __shared__ u16 kEs[LL][18];         // 18432 B
  __shared__ float qEs[16][17];       // 1088 B
  __shared__ float hist[4][64][17];   // 17408 B, lane-private
  __shared__ float osh[16][33];       // 2112 B, cross-wave merge

  {
    const u32* gs = (const u32*)(kEbf + (((size_t)(b * HH + h)) * LL) * 16);
    u32* ls = (u32*)(&kEs[0][0]);
#pragma unroll
    for (int t = 0; t < 16; ++t) {
      int idx = t * 256 + tid;
      int r = idx >> 3, c = idx & 7;
      ls[r * 9 + c] = gs[idx];
    }
  }
  if (tid < 224) {
    int r = tid / 14, d = tid % 14;
    qEs[r][d] = qE2[(((size_t)(b * HH + h)) * LL + row0 + r) * NDB + d];
  }
  {
    float* hf = &hist[0][0][0];
#pragma unroll
    for (int t = 0; t < 17; ++t) hf[t * 256 + tid] = 0.f;
  }
  if (tid < 132) ((float4*)&osh[0][0])[tid] = float4{0.f, 0.f, 0.f, 0.f};

  const bf16x8 aQ = *(const bf16x8*)(qkv + ((size_t)(b * LL + row0 + lr)) * QKS + h * KHD + lg * 8);

  __syncthreads();

  const f32x4 zero4 = {0.f, 0.f, 0.f, 0.f};
  const int keyA = 8 * (lr >> 2) + (lr & 3);
  const u16* kbase = qkv + (size_t)b * LL * QKS + 512 + h * KHD + lg * 8;
  const u16* vbase = vtbf + ((size_t)(b * HH + h) * KHD) * LL + lg * 8;
  const unsigned char* drow = didx + ((size_t)(b * LL) + row0 + lr) * LL + 8 * lg;
  float* hlane = &hist[w][lane][0];

  // ---- phase 1: issue ALL global loads (20 in flight); fence forbids sinking ----
  bf16x8 kA[4], kB[4], v0r[4], v1r[4];
  uint2 dv[4];
#pragma unroll
  for (int ct = 0; ct < 4; ++ct) {
    const int x0 = w * 128 + ct * 32;
    kA[ct] = *(const bf16x8*)(kbase + (size_t)(x0 + keyA) * QKS);
    kB[ct] = *(const bf16x8*)(kbase + (size_t)(x0 + keyA + 4) * QKS);
    dv[ct] = *(const uint2*)(drow + x0);
    v0r[ct] = *(const bf16x8*)(vbase + (size_t)lr * LL + x0);
    v1r[ct] = *(const bf16x8*)(vbase + (size_t)(16 + lr) * LL + x0);
  }
  __builtin_amdgcn_sched_barrier(0);

  // ---- phase 2: per-chunk compute (chunks independent) ----
  f32x4 o0 = zero4, o1 = zero4;
#pragma unroll
  for (int ct = 0; ct < 4; ++ct) {
    const int x0 = w * 128 + ct * 32;
    f32x4 sA = __builtin_amdgcn_mfma_f32_16x16x32_bf16(kA[ct], aQ, zero4, 0, 0, 0);
    f32x4 sB = __builtin_amdgcn_mfma_f32_16x16x32_bf16(kB[ct], aQ, zero4, 0, 0, 0);
    float pA[4], pB[4];
#pragma unroll
    for (int q = 0; q < 4; ++q) {
      const int da = (dv[ct].x >> (8 * q)) & 0xff;
      const int db = (dv[ct].y >> (8 * q)) & 0xff;
      pA[q] = __expf(sA[q] + qEs[lr][da] + bf2f(kEs[x0 + 8 * lg + q][da]));
      pB[q] = __expf(sB[q] + qEs[lr][db] + bf2f(kEs[x0 + 8 * lg + 4 + q][db]));
      hlane[da] += pA[q];
      hlane[db] += pB[q];
    }
    u32x4 pw;
    pw[0] = cvt_pk_bf16(pA[0], pA[1]);
    pw[1] = cvt_pk_bf16(pA[2], pA[3]);
    pw[2] = cvt_pk_bf16(pB[0], pB[1]);
    pw[3] = cvt_pk_bf16(pB[2], pB[3]);
    bf16x8 aP = __builtin_bit_cast(bf16x8, pw);
    o0 = __builtin_amdgcn_mfma_f32_16x16x32_bf16(aP, v0r[ct], o0, 0, 0, 0);
    o1 = __builtin_amdgcn_mfma_f32_16x16x32_bf16(aP, v1r[ct], o1, 0, 0, 0);
  }

  // merge O partials across the 4 kv-split waves
#pragma unroll
  for (int q = 0; q < 4; ++q) {
    const int rl = lg * 4 + q;
    atomicAdd(&osh[rl][lr], o0[q]);
    atomicAdd(&osh[rl][16 + lr], o1[q]);
  }
  __syncthreads();

  // epilogue: thread (r,c) -> z directly; rsum/vbias from hist
  const int r = tid >> 4, c = tid & 15;
  float ht[NDB];
  float rsum = 0.f;
#pragma unroll
  for (int d = 0; d < NDB; ++d) {
    float a = 0.f;
#pragma unroll
    for (int ww = 0; ww < 4; ++ww)
#pragma unroll
      for (int gg = 0; gg < 4; ++gg) a += hist[ww][r + 16 * gg][d];
    ht[d] = a;
    rsum += a;
  }
  const float inv = 1.0f / rsum;
  float vb_0 = 0.f, vb_1 = 0.f;
#pragma unroll
  for (int d = 0; d < NDB; ++d) {
    vb_0 += ht[d] * Vsum[d * KHD + c];
    vb_1 += ht[d] * Vsum[d * KHD + 16 + c];
  }
  const size_t orow = ((size_t)(b * LL + row0 + r)) * DDIM + h * KHD;
  z[orow + c] = f2bf((osh[r][c] + vb_0) * inv);
  z[orow + 16 + c] = f2bf((osh[r][16 + c] + vb_1) * inv);
}

// ---------------- out = LN(X + Y), f32 + bf16 ----------------
__global__ __launch_bounds__(256) void add_ln_kernel(
    const float* __restrict__ X, const float* __restrict__ Y,
    const float* __restrict__ g, const float* __restrict__ be,
    float* __restrict__ out, u16* __restrict__ outb) {
  const int row = blockIdx.x, tid = threadIdx.x;
  const int lane = tid & 63, wid = tid >> 6;
  __shared__ float red[4];
  const size_t base = (size_t)row * DDIM;
  float x0 = X[base + tid] + Y[base + tid];
  float x1 = X[base + tid + 256] + Y[base + tid + 256];
  float s = wredSum(x0 + x1);
  if (lane == 0) red[wid] = s;
  __syncthreads();
  float mu = (red[0] + red[1] + red[2] + red[3]) * (1.0f / DDIM);
  __syncthreads();
  float d0 = x0 - mu, d1 = x1 - mu;
  float vs = wredSum(d0 * d0 + d1 * d1);
  if (lane == 0) red[wid] = vs;
  __syncthreads();
  float var = (red[0] + red[1] + red[2] + red[3]) * (1.0f / DDIM);
  float inv = rsqrtf(var + 1e-5f);
  float r0 = d0 * inv * g[tid] + be[tid];
  float r1 = d1 * inv * g[tid + 256] + be[tid + 256];
  out[base + tid] = r0;
  out[base + tid + 256] = r1;
  outb[base + tid] = f2bf(r0);
  outb[base + tid + 256] = f2bf(r1);
}

// ---------------- pool v2 ----------------
__global__ __launch_bounds__(256) void pool2_kernel(const float* __restrict__ h, float* __restrict__ pooled) {
  const int s = blockIdx.x, b = blockIdx.y, tid = threadIdx.x;
  float a0 = 0.f, a1 = 0.f;
  const float* base = h + ((size_t)(b * LL) + s * 64) * DDIM;
#pragma unroll 4
  for (int l = 0; l < 64; ++l) {
    a0 += base[(size_t)l * DDIM + tid];
    a1 += base[(size_t)l * DDIM + tid + 256];
  }
  atomicAdd(&pooled[b * DDIM + tid], a0);
  atomicAdd(&pooled[b * DDIM + tid + 256], a1);
}

// ---------------- head stage 1 ----------------
__global__ __launch_bounds__(256) void head1_kernel(
    const float* __restrict__ pooled, const float* __restrict__ Wm1, float* __restrict__ hidden) {
  const int s = blockIdx.x, b = blockIdx.y, tid = threadIdx.x;
  __shared__ float pl[64];
  if (tid < 64) pl[tid] = pooled[b * DDIM + s * 64 + tid];
  __syncthreads();
  float a0 = 0.f, a1 = 0.f;
  const float* wbase = Wm1 + (size_t)(s * 64) * MMD;
#pragma unroll 8
  for (int dd = 0; dd < 64; ++dd) {
    float p = pl[dd];
    a0 += p * wbase[(size_t)dd * MMD + tid];
    a1 += p * wbase[(size_t)dd * MMD + tid + 256];
  }
  atomicAdd(&hidden[b * MMD + tid], a0);
  atomicAdd(&hidden[b * MMD + tid + 256], a1);
}

// ---------------- head stage 2 ----------------
__global__ __launch_bounds__(256) void head2_kernel(
    const float* __restrict__ hidden, const float* __restrict__ bm1,
    const float* __restrict__ Wm2, const float* __restrict__ bm2, float* __restrict__ out) {
  const int b = blockIdx.x, tid = threadIdx.x;
  float part = 0.f;
#pragma unroll
  for (int jj = 0; jj < 2; ++jj) {
    int j = tid + jj * 256;
    part += fmaxf(hidden[b * MMD + j] + bm1[j], 0.f) * Wm2[j];
  }
  __shared__ float red[4];
  int lane = tid & 63, wid = tid >> 6;
  float ssum = wredSum(part);
  if (lane == 0) red[wid] = ssum;
  __syncthreads();
  if (tid == 0) out[b] = red[0] + red[1] + red[2] + red[3] + bm2[0];
}

extern "C" void kernel_launch(void* const* d_in, const int* in_sizes, int n_in,
                              void* d_out, int out_size, void* d_ws, size_t ws_size,
                              hipStream_t stream) {
  const int* cell_types = (const int*)d_in[0];
  const float* distances = (const float*)d_in[1];
  const float* cell_emb = (const float*)d_in[2];
  const float* Kqk = (const float*)d_in[3];
  const float* Kqr = (const float*)d_in[4];
  const float* Kkr = (const float*)d_in[5];
  const float* Vqk = (const float*)d_in[6];
  const float* Vqr = (const float*)d_in[7];
  const float* Vkr = (const float*)d_in[8];
  const float* Wq = (const float*)d_in[9];
  const float* Wk = (const float*)d_in[10];
  const float* Wv = (const float*)d_in[11];
  const float* Wo = (const float*)d_in[12];
  const float* bq = (const float*)d_in[13];
  const float* bk = (const float*)d_in[14];
  const float* bv = (const float*)d_in[15];
  const float* bo = (const float*)d_in[16];
  const float* W1 = (const float*)d_in[17];
  const float* b1 = (const float*)d_in[18];
  const float* W2 = (const float*)d_in[19];
  const float* b2 = (const float*)d_in[20];
  const float* g1 = (const float*)d_in[21];
  const float* be1 = (const float*)d_in[22];
  const float* g2 = (const float*)d_in[23];
  const float* be2 = (const float*)d_in[24];
  const float* Wm1 = (const float*)d_in[25];
  const float* bm1 = (const float*)d_in[26];
  const float* Wm2 = (const float*)d_in[27];
  const float* bm2 = (const float*)d_in[28];

  char* w = (char*)d_ws;
  auto alloc = [&](size_t bytes) { void* p = (void*)w; w += (bytes + 255) & ~(size_t)255; return p; };
  unsigned char* didx = (unsigned char*)alloc(sizeof(unsigned char) * BB * LL * LL);
  float* h    = (float*)alloc(sizeof(float) * BB * LL * DDIM);
  u16* hbf    = (u16*)alloc(sizeof(u16) * BB * LL * DDIM);
  float* h2   = (float*)alloc(sizeof(float) * BB * LL * DDIM);
  u16* h2bf   = (u16*)alloc(sizeof(u16) * BB * LL * DDIM);
  u16* qkvbf  = (u16*)alloc(sizeof(u16) * BB * LL * QKS);
  float* ob   = (float*)alloc(sizeof(float) * BB * LL * DDIM);
  u16* f1bf   = (u16*)alloc(sizeof(u16) * BB * LL * FFD);
  u16* zbf    = (u16*)alloc(sizeof(u16) * BB * LL * DDIM);
  u16* vtbf   = (u16*)alloc(sizeof(u16) * BB * HH * KHD * LL);
  float* qE2  = (float*)alloc(sizeof(float) * BB * HH * LL * NDB);
  u16* kEbf   = (u16*)alloc(sizeof(u16) * (size_t)BB * HH * LL * 16);
  u16* Wqkvt  = (u16*)alloc(sizeof(u16) * (size_t)NLAY * QKS * DDIM);
  u16* Wot    = (u16*)alloc(sizeof(u16) * (size_t)NLAY * DDIM * DDIM);
  u16* W1t    = (u16*)alloc(sizeof(u16) * (size_t)NLAY * FFD * DDIM);
  u16* W2t    = (u16*)alloc(sizeof(u16) * (size_t)NLAY * DDIM * FFD);
  float* bqkv = (float*)alloc(sizeof(float) * NLAY * QKS);
  float* Vsum = (float*)alloc(sizeof(float) * NDB * KHD);
  float* EkrS = (float*)alloc(sizeof(float) * NDB);
  float* pooled = (float*)alloc(sizeof(float) * BB * DDIM);
  float* hidden = (float*)alloc(sizeof(float) * BB * MMD);

  const int Mrows = BB * LL;

  bucketize_kernel<<<(BB * LL * LL / 4 + 255) / 256, 256, 0, stream>>>(distances, didx, BB * LL * LL / 4);
  embed_kernel<<<(BB * LL * DDIM + 255) / 256, 256, 0, stream>>>(cell_types, cell_emb, h, hbf, BB * LL * DDIM);
  prep_kernel<<<1, 512, 0, stream>>>(Vqk, Vqr, Vkr, Kkr, Vsum, EkrS);
  biaspack_kernel<<<(NLAY * QKS + 255) / 256, 256, 0, stream>>>(bq, bk, bv, bqkv);
  hipMemsetAsync(pooled, 0, sizeof(float) * BB * DDIM, stream);
  hipMemsetAsync(hidden, 0, sizeof(float) * BB * MMD, stream);

  for (int lay = 0; lay < NLAY; ++lay) {
    wconv_layer<<<768, 256, 0, stream>>>(
        Wq + (size_t)lay * DDIM * DDIM, Wk + (size_t)lay * DDIM * DDIM,
        Wv + (size_t)lay * DDIM * DDIM, Wo + (size_t)lay * DDIM * DDIM,
        W1 + (size_t)lay * DDIM * FFD, W2 + (size_t)lay * FFD * DDIM,
        Wqkvt + (size_t)lay * QKS * DDIM, Wot + (size_t)lay * DDIM * DDIM,
        W1t + (size_t)lay * FFD * DDIM, W2t + (size_t)lay * DDIM * FFD);
  }

  const int nrel = BB * HH * LL * NDB;

  for (int lay = 0; lay < NLAY; ++lay) {
    gemm_bf16<<<dim3((Mrows / 32) * (QKS / 64)), 256, 0, stream>>>(
        hbf, Wqkvt + (size_t)lay * QKS * DDIM, bqkv + (size_t)lay * QKS,
        nullptr, qkvbf, Mrows, QKS, DDIM, 0, 512);

    proj_qk_kernel<<<(nrel + 255) / 256, 256, 0, stream>>>(qkvbf, Kqk, Kqr, EkrS, qE2, kEbf);
    vtrans_kernel<<<dim3(HH, BB), 256, 0, stream>>>(qkvbf, vtbf);
    attn_fused_kernel<<<dim3(2048), 256, 0, stream>>>(qkvbf, vtbf, qE2, kEbf, didx, Vsum, zbf);

    gemm_bf16<<<dim3((Mrows / 32) * (DDIM / 64)), 256, 0, stream>>>(
        zbf, Wot + (size_t)lay * DDIM * DDIM, bo + (size_t)lay * DDIM, ob, nullptr, Mrows, DDIM, DDIM, 0, 0);
    add_ln_kernel<<<Mrows, 256, 0, stream>>>(h, ob, g1 + (size_t)lay * DDIM, be1 + (size_t)lay * DDIM, h2, h2bf);
    gemm_bf16<<<dim3((Mrows / 32) * (FFD / 64)), 256, 0, stream>>>(
        h2bf, W1t + (size_t)lay * FFD * DDIM, b1 + (size_t)lay * FFD, nullptr, f1bf, Mrows, FFD, DDIM, 1, 0);
    gemm_bf16<<<dim3((Mrows / 32) * (DDIM / 64)), 256, 0, stream>>>(
        f1bf, W2t + (size_t)lay * DDIM * FFD, b2 + (size_t)lay * DDIM, ob, nullptr, Mrows, DDIM, FFD, 0, 0);
    add_ln_kernel<<<Mrows, 256, 0, stream>>>(h2, ob, g2 + (size_t)lay * DDIM, be2 + (size_t)lay * DDIM, h, hbf);
  }

  pool2_kernel<<<dim3(8, BB), 256, 0, stream>>>(h, pooled);
  head1_kernel<<<dim3(8, BB), 256, 0, stream>>>(pooled, Wm1, hidden);
  head2_kernel<<<BB, 256, 0, stream>>>(hidden, bm1, Wm2, bm2, (float*)d_out);
}

// Round 16
// 977.063 us; speedup vs baseline: 1.1369x; 1.1369x over previous
//
#include <hip/hip_runtime.h>
#include <math.h>

#define NLAY 8
#define BB 4
#define LL 512
#define DDIM 512
#define HH 16
#define KHD 32
#define FFD 2048
#define MMD 512
#define NDB 14
#define QKS 1536
#define SCALEF 0.17677669529663687f

typedef unsigned short u16;
typedef unsigned int u32;
typedef __attribute__((ext_vector_type(8))) short bf16x8;
typedef __attribute__((ext_vector_type(4))) float f32x4;
typedef __attribute__((ext_vector_type(4))) u32 u32x4;

__device__ __forceinline__ u16 f2bf(float f) {
  unsigned u = __builtin_bit_cast(unsigned, f);
  u = (u + 0x7fffu + ((u >> 16) & 1u)) >> 16;
  return (u16)u;
}
__device__ __forceinline__ float bf2f(u16 v) {
  unsigned u = ((unsigned)v) << 16;
  return __builtin_bit_cast(float, u);
}
__device__ __forceinline__ u32 cvt_pk_bf16(float lo, float hi) {
  u32 r;
  asm("v_cvt_pk_bf16_f32 %0, %1, %2" : "=v"(r) : "v"(lo), "v"(hi));
  return r;
}
__device__ __forceinline__ float wredSum(float v) {
#pragma unroll
  for (int o = 32; o > 0; o >>= 1) v += __shfl_down(v, o);
  return v;
}
__device__ __forceinline__ void gload_lds16(const u16* g, u16* l) {
  __builtin_amdgcn_global_load_lds((const __attribute__((address_space(1))) void*)g,
                                   (__attribute__((address_space(3))) void*)l, 16, 0, 0);
}

// ---------------- bucketize -> uint8, [b][l][x] layout ----------------
__global__ void bucketize_kernel(const float* __restrict__ dist, unsigned char* __restrict__ didx, int n) {
  int i = blockIdx.x * 256 + threadIdx.x;
  if (i >= n) return;
  float4 v = ((const float4*)dist)[i];
  float vv[4] = {v.x, v.y, v.z, v.w};
  unsigned char o[4];
#pragma unroll
  for (int j = 0; j < 4; ++j) {
    int c = 0;
#pragma unroll
    for (int s = 1; s <= NDB; ++s) c += (10.0f * (float)s < vv[j]) ? 1 : 0;
    o[j] = (unsigned char)(c > (NDB - 1) ? (NDB - 1) : c);
  }
  *(uchar4*)(didx + i * 4) = *(uchar4*)o;
}

// ---------------- h = cell_emb[cell_types] (f32 + bf16) ----------------
__global__ void embed_kernel(const int* __restrict__ ct, const float* __restrict__ emb,
                             float* __restrict__ h, u16* __restrict__ hbf, int n) {
  int i = blockIdx.x * 256 + threadIdx.x;
  if (i >= n) return;
  int bl = i >> 9, d = i & 511;
  float v = emb[ct[bl] * DDIM + d];
  h[i] = v;
  hbf[i] = f2bf(v);
}

// ---------------- Vsum, EkrS ----------------
__global__ void prep_kernel(const float* __restrict__ Vqk, const float* __restrict__ Vqr,
                            const float* __restrict__ Vkr, const float* __restrict__ Kkr,
                            float* __restrict__ Vsum, float* __restrict__ EkrS) {
  int tid = threadIdx.x;
  if (tid < NDB * KHD) Vsum[tid] = Vqk[tid] + Vqr[tid] + Vkr[tid];
  if (tid < NDB) {
    float s = 0.f;
    for (int kk = 0; kk < KHD; ++kk) s += Kkr[tid * KHD + kk];
    EkrS[tid] = s;
  }
}

// ---------------- packed qkv bias [NLAY][1536] ----------------
__global__ void biaspack_kernel(const float* __restrict__ bq, const float* __restrict__ bk,
                                const float* __restrict__ bv, float* __restrict__ bqkv) {
  int i = blockIdx.x * 256 + threadIdx.x;
  if (i >= NLAY * QKS) return;
  int lay = i / QKS, c = i % QKS;
  float v;
  if (c < 512) v = bq[lay * DDIM + c];
  else if (c < 1024) v = bk[lay * DDIM + c - 512];
  else v = bv[lay * DDIM + c - 1024];
  bqkv[i] = v;
}

// ---------------- weight transpose+convert ----------------
__device__ __forceinline__ void wtconv_tile(const float* __restrict__ src, u16* __restrict__ dst,
                                            int K, int N, int tn, int tk) {
  __shared__ float tl[64][65];
  const int t = threadIdx.x;
#pragma unroll
  for (int p = 0; p < 4; ++p) {
    int k = tk * 64 + p * 16 + (t >> 4);
    int n = tn * 64 + (t & 15) * 4;
    float4 v = *(const float4*)(src + (size_t)k * N + n);
    tl[(t & 15) * 4 + 0][p * 16 + (t >> 4)] = v.x;
    tl[(t & 15) * 4 + 1][p * 16 + (t >> 4)] = v.y;
    tl[(t & 15) * 4 + 2][p * 16 + (t >> 4)] = v.z;
    tl[(t & 15) * 4 + 3][p * 16 + (t >> 4)] = v.w;
  }
  __syncthreads();
  int n = t >> 2, cc = t & 3;
  u16 o[16];
#pragma unroll
  for (int e = 0; e < 16; ++e) o[e] = f2bf(tl[n][cc * 16 + e]);
  u16* dp = dst + (size_t)(tn * 64 + n) * K + tk * 64 + cc * 16;
  *(uint4*)(dp) = *(uint4*)&o[0];
  *(uint4*)(dp + 8) = *(uint4*)&o[8];
}

__global__ __launch_bounds__(256) void wconv_layer(
    const float* __restrict__ Wq, const float* __restrict__ Wk, const float* __restrict__ Wv,
    const float* __restrict__ Wo, const float* __restrict__ W1, const float* __restrict__ W2,
    u16* __restrict__ Wqkvt, u16* __restrict__ Wot, u16* __restrict__ W1t, u16* __restrict__ W2t) {
  int b = blockIdx.x;
  if (b < 64) { wtconv_tile(Wq, Wqkvt, 512, 512, b >> 3, b & 7); return; }
  if (b < 128) { b -= 64; wtconv_tile(Wk, Wqkvt + 512 * 512, 512, 512, b >> 3, b & 7); return; }
  if (b < 192) { b -= 128; wtconv_tile(Wv, Wqkvt + 1024 * 512, 512, 512, b >> 3, b & 7); return; }
  if (b < 256) { b -= 192; wtconv_tile(Wo, Wot, 512, 512, b >> 3, b & 7); return; }
  if (b < 512) { b -= 256; wtconv_tile(W1, W1t, 512, FFD, b >> 3, b & 7); return; }
  b -= 512; wtconv_tile(W2, W2t, FFD, 512, b >> 5, b & 31);
}

// ---------------- bf16 MFMA GEMM: 32x64 tile, BK=64, 4 waves (2x2), XCD y-chunked swizzle ----------------
// TAG 0 = QKV (writes packed bf16 q/k + V transposed into vt), 1 = O (f32), 2 = FF1 (gelu bf16), 3 = FF2 (f32)
template <int TAG>
__global__ __launch_bounds__(256) void gemm_bf16(
    const u16* __restrict__ A, const u16* __restrict__ Bt, const float* __restrict__ bias,
    float* __restrict__ Cf, u16* __restrict__ Cb, u16* __restrict__ Vt,
    int M, int N, int K) {
  __shared__ u16 As[32 * 64];
  __shared__ u16 Bs[64 * 64];
  const int tid = threadIdx.x, w = tid >> 6, lane = tid & 63;
  const int lr = lane & 15, lg = lane >> 4;
  const int wr = w >> 1, wc = w & 1;
  const int gx = N >> 6;
  const int bi = blockIdx.x;
  const int xcd = bi & 7, rr = bi >> 3;
  const int y = xcd * 8 + rr / gx, x = rr % gx;
  const int row0 = y * 32, col0 = x * 64;
  const int srow = lane >> 3;
  const int aoff = ((lane & 7) ^ srow) * 8;
  const f32x4 z4 = {0.f, 0.f, 0.f, 0.f};
  f32x4 acc[2] = {z4, z4};

  for (int k0 = 0; k0 < K; k0 += 64) {
    gload_lds16(A + (size_t)(row0 + w * 8 + srow) * K + k0 + aoff, As + (w * 8) * 64);
#pragma unroll
    for (int i = 0; i < 2; ++i)
      gload_lds16(Bt + (size_t)(col0 + w * 16 + i * 8 + srow) * K + k0 + aoff,
                  Bs + (w * 16 + i * 8) * 64);
    __syncthreads();
#pragma unroll
    for (int kh = 0; kh < 2; ++kh) {
      bf16x8 a, b[2];
      {
        int r = wr * 16 + lr;
        a = *(const bf16x8*)(As + r * 64 + (((kh * 4 + lg) ^ (r & 7)) << 3));
      }
#pragma unroll
      for (int ni = 0; ni < 2; ++ni) {
        int r = wc * 32 + ni * 16 + lr;
        b[ni] = *(const bf16x8*)(Bs + r * 64 + (((kh * 4 + lg) ^ (r & 7)) << 3));
      }
#pragma unroll
      for (int ni = 0; ni < 2; ++ni)
        acc[ni] = __builtin_amdgcn_mfma_f32_16x16x32_bf16(a, b[ni], acc[ni], 0, 0, 0);
    }
    __syncthreads();
  }
  {
    int r = row0 + wr * 16 + lg * 4;
#pragma unroll
    for (int ni = 0; ni < 2; ++ni) {
      int c = col0 + wc * 32 + ni * 16 + lr;
      float bs = bias[c];
#pragma unroll
      for (int j = 0; j < 4; ++j) {
        float v = acc[ni][j] + bs;
        int rg = r + j;
        size_t idx = (size_t)rg * N + c;
        if (TAG == 0) {
          // QKV: q (c<512) scaled+packed bf16; k (512..1023) packed bf16; v (>=1024) -> vt transposed
          if (c < 1024) {
            Cb[idx] = f2bf(c < 512 ? v * SCALEF : v);
          } else {
            int cc = c - 1024, hh = cc >> 5, kh2 = cc & 31;
            int bb = rg >> 9, l = rg & 511;
            Vt[(((size_t)(bb * HH + hh)) * KHD + kh2) * LL + l] = f2bf(v);
          }
        } else if (TAG == 2) {
          v = 0.5f * v * (1.0f + erff(v * 0.70710678118654752f));
          Cb[idx] = f2bf(v);
        } else {
          Cf[idx] = v;
        }
      }
    }
  }
}

// ---------------- merged rel projections: qE2 (f32) + kEbf (bf16 [bhl][16]) ----------------
__global__ void proj_qk_kernel(const u16* __restrict__ qkv, const float* __restrict__ Kqk,
                               const float* __restrict__ Kqr, const float* __restrict__ ekrs,
                               float* __restrict__ qE2, u16* __restrict__ kEbf) {
  int idx = blockIdx.x * 256 + threadIdx.x;
  if (idx >= BB * HH * LL * NDB) return;
  int d = idx % NDB;
  int rest = idx / NDB;
  int l = rest & (LL - 1);
  int bh = rest >> 9;
  int h = bh & (HH - 1);
  int b = bh >> 4;
  const u16* qr_ = qkv + ((size_t)(b * LL + l)) * QKS + h * KHD;
  const u16* kr_ = qr_ + 512;
  const float* kq = Kqk + d * KHD;
  const float* kk2 = Kqr + d * KHD;
  float sq = 0.f, sk = 0.f;
#pragma unroll
  for (int kk = 0; kk < KHD; ++kk) {
    sq += bf2f(qr_[kk]) * kq[kk];
    sk += bf2f(kr_[kk]) * kk2[kk];
  }
  qE2[idx] = sq;  // q pre-scaled by SCALEF in QKV epilogue
  kEbf[(size_t)rest * 16 + d] = f2bf(sk * SCALEF + SCALEF * ekrs[d]);
}

// ---------------- attn A: batched loads via sched_barrier (round-13 structure) ----------------
__global__ __launch_bounds__(256) void attn_exp_kernel(
    const u16* __restrict__ qkv, const float* __restrict__ qE2, const u16* __restrict__ kEbf,
    const unsigned char* __restrict__ didx, const float* __restrict__ Vsum,
    u16* __restrict__ E, float* __restrict__ vbias, float* __restrict__ invs) {
  const int i = blockIdx.x;
  const int j = i >> 3;
  const int g = (i & 7) * 8 + (j >> 5);
  const int qr = j & 31;
  const int h = g & 15, b = g >> 4;
  const int tid = threadIdx.x, lane = tid & 63, w = tid >> 6;
  const int lr = lane & 15, lg = lane >> 4;
  const int row0 = qr * 16;

  __shared__ u16 kEs[LL][18];
  __shared__ float qEs[16][17];
  __shared__ float hist[4][64][17];

  {
    const u32* gs = (const u32*)(kEbf + (((size_t)(b * HH + h)) * LL) * 16);
    u32* ls = (u32*)(&kEs[0][0]);
#pragma unroll
    for (int t = 0; t < 16; ++t) {
      int idx = t * 256 + tid;
      int r = idx >> 3, c = idx & 7;
      ls[r * 9 + c] = gs[idx];
    }
  }
  if (tid < 224) {
    int r = tid / 14, d = tid % 14;
    qEs[r][d] = qE2[(((size_t)(b * HH + h)) * LL + row0 + r) * NDB + d];
  }
  {
    float* hf = &hist[0][0][0];
#pragma unroll
    for (int t = 0; t < 17; ++t) hf[t * 256 + tid] = 0.f;
  }

  const bf16x8 aQ = *(const bf16x8*)(qkv + ((size_t)(b * LL + row0 + lr)) * QKS + h * KHD + lg * 8);

  __syncthreads();

  const f32x4 zero4 = {0.f, 0.f, 0.f, 0.f};
  const int keyA = 8 * (lr >> 2) + (lr & 3);
  const u16* kbase = qkv + (size_t)b * LL * QKS + 512 + h * KHD + lg * 8;
  const unsigned char* drow = didx + ((size_t)(b * LL) + row0 + lr) * LL + 8 * lg;
  u16* Ebase = E + ((((size_t)(b * HH + h)) * LL) + row0 + lr) * LL + 8 * lg;
  float* hlane = &hist[w][lane][0];

  bf16x8 kA[4], kB[4];
  uint2 dv[4];
#pragma unroll
  for (int ct = 0; ct < 4; ++ct) {
    const int x0 = w * 128 + ct * 32;
    kA[ct] = *(const bf16x8*)(kbase + (size_t)(x0 + keyA) * QKS);
    kB[ct] = *(const bf16x8*)(kbase + (size_t)(x0 + keyA + 4) * QKS);
    dv[ct] = *(const uint2*)(drow + x0);
  }
  __builtin_amdgcn_sched_barrier(0);   // 12 loads stay in flight

#pragma unroll
  for (int ct = 0; ct < 4; ++ct) {
    const int x0 = w * 128 + ct * 32;
    f32x4 sA = __builtin_amdgcn_mfma_f32_16x16x32_bf16(kA[ct], aQ, zero4, 0, 0, 0);
    f32x4 sB = __builtin_amdgcn_mfma_f32_16x16x32_bf16(kB[ct], aQ, zero4, 0, 0, 0);
    float pA[4], pB[4];
#pragma unroll
    for (int q = 0; q < 4; ++q) {
      const int da = (dv[ct].x >> (8 * q)) & 0xff;
      const int db = (dv[ct].y >> (8 * q)) & 0xff;
      pA[q] = __expf(sA[q] + qEs[lr][da] + bf2f(kEs[x0 + 8 * lg + q][da]));
      pB[q] = __expf(sB[q] + qEs[lr][db] + bf2f(kEs[x0 + 8 * lg + 4 + q][db]));
      hlane[da] += pA[q];
      hlane[db] += pB[q];
    }
    u32x4 pw;
    pw[0] = cvt_pk_bf16(pA[0], pA[1]);
    pw[1] = cvt_pk_bf16(pA[2], pA[3]);
    pw[2] = cvt_pk_bf16(pB[0], pB[1]);
    pw[3] = cvt_pk_bf16(pB[2], pB[3]);
    *(u32x4*)(Ebase + x0) = pw;
  }

  __syncthreads();

  const int r = tid >> 4, c = tid & 15;
  float ht[NDB];
  float rsum = 0.f;
#pragma unroll
  for (int d = 0; d < NDB; ++d) {
    float a = 0.f;
#pragma unroll
    for (int ww = 0; ww < 4; ++ww)
#pragma unroll
      for (int gg = 0; gg < 4; ++gg) a += hist[ww][r + 16 * gg][d];
    ht[d] = a;
    rsum += a;
  }
  float vb_0 = 0.f, vb_1 = 0.f;
#pragma unroll
  for (int d = 0; d < NDB; ++d) {
    vb_0 += ht[d] * Vsum[d * KHD + c];
    vb_1 += ht[d] * Vsum[d * KHD + 16 + c];
  }
  const size_t rowi = (((size_t)(b * HH + h)) * LL) + row0 + r;
  vbias[rowi * KHD + c] = vb_0;
  vbias[rowi * KHD + 16 + c] = vb_1;
  if (c == 0) invs[rowi] = 1.0f / rsum;
}

// ---------------- attn B: z = (E @ V^T + vbias) * inv ----------------
__global__ __launch_bounds__(256) void attn_pv_kernel(
    const u16* __restrict__ E, const u16* __restrict__ vtbf,
    const float* __restrict__ vbias, const float* __restrict__ invs,
    u16* __restrict__ z) {
  const int i = blockIdx.x;
  const int j = i >> 3;
  const int g = (i & 7) * 8 + (j >> 3);
  const int qt = j & 7;
  const int h = g & 15, b = g >> 4;
  const int tid = threadIdx.x, lane = tid & 63, w = tid >> 6;
  const int lr = lane & 15, lg = lane >> 4;
  const int row0 = qt * 64 + w * 16;

  f32x4 o0 = {0.f, 0.f, 0.f, 0.f}, o1 = {0.f, 0.f, 0.f, 0.f};
  const u16* Ebase = E + ((((size_t)(b * HH + h)) * LL) + row0 + lr) * LL + lg * 8;
  const u16* vbase = vtbf + ((size_t)(b * HH + h) * KHD) * LL + lg * 8;

#pragma unroll 4
  for (int ct = 0; ct < 16; ++ct) {
    const int x0 = ct * 32;
    bf16x8 aE = *(const bf16x8*)(Ebase + x0);
    bf16x8 vb0 = *(const bf16x8*)(vbase + (size_t)lr * LL + x0);
    bf16x8 vb1 = *(const bf16x8*)(vbase + (size_t)(16 + lr) * LL + x0);
    o0 = __builtin_amdgcn_mfma_f32_16x16x32_bf16(aE, vb0, o0, 0, 0, 0);
    o1 = __builtin_amdgcn_mfma_f32_16x16x32_bf16(aE, vb1, o1, 0, 0, 0);
  }

#pragma unroll
  for (int q = 0; q < 4; ++q) {
    const int rl = lg * 4 + q;
    const size_t rowi = (((size_t)(b * HH + h)) * LL) + row0 + rl;
    const float inv = invs[rowi];
    const float v0 = vbias[rowi * KHD + lr];
    const float v1 = vbias[rowi * KHD + 16 + lr];
    const size_t orow = ((size_t)(b * LL + row0 + rl)) * DDIM + h * KHD;
    z[orow + lr] = f2bf((o0[q] + v0) * inv);
    z[orow + 16 + lr] = f2bf((o1[q] + v1) * inv);
  }
}

// ---------------- out = LN(X + Y), f32 + bf16 ----------------
__global__ __launch_bounds__(256) void add_ln_kernel(
    const float* __restrict__ X, const float* __restrict__ Y,
    const float* __restrict__ g, const float* __restrict__ be,
    float* __restrict__ out, u16* __restrict__ outb) {
  const int row = blockIdx.x, tid = threadIdx.x;
  const int lane = tid & 63, wid = tid >> 6;
  __shared__ float red[4];
  const size_t base = (size_t)row * DDIM;
  float x0 = X[base + tid] + Y[base + tid];
  float x1 = X[base + tid + 256] + Y[base + tid + 256];
  float s = wredSum(x0 + x1);
  if (lane == 0) red[wid] = s;
  __syncthreads();
  float mu = (red[0] + red[1] + red[2] + red[3]) * (1.0f / DDIM);
  __syncthreads();
  float d0 = x0 - mu, d1 = x1 - mu;
  float vs = wredSum(d0 * d0 + d1 * d1);
  if (lane == 0) red[wid] = vs;
  __syncthreads();
  float var = (red[0] + red[1] + red[2] + red[3]) * (1.0f / DDIM);
  float inv = rsqrtf(var + 1e-5f);
  float r0 = d0 * inv * g[tid] + be[tid];
  float r1 = d1 * inv * g[tid + 256] + be[tid + 256];
  out[base + tid] = r0;
  out[base + tid + 256] = r1;
  outb[base + tid] = f2bf(r0);
  outb[base + tid + 256] = f2bf(r1);
}

// ---------------- pool v2 ----------------
__global__ __launch_bounds__(256) void pool2_kernel(const float* __restrict__ h, float* __restrict__ pooled) {
  const int s = blockIdx.x, b = blockIdx.y, tid = threadIdx.x;
  float a0 = 0.f, a1 = 0.f;
  const float* base = h + ((size_t)(b * LL) + s * 64) * DDIM;
#pragma unroll 4
  for (int l = 0; l < 64; ++l) {
    a0 += base[(size_t)l * DDIM + tid];
    a1 += base[(size_t)l * DDIM + tid + 256];
  }
  atomicAdd(&pooled[b * DDIM + tid], a0);
  atomicAdd(&pooled[b * DDIM + tid + 256], a1);
}

// ---------------- head stage 1 ----------------
__global__ __launch_bounds__(256) void head1_kernel(
    const float* __restrict__ pooled, const float* __restrict__ Wm1, float* __restrict__ hidden) {
  const int s = blockIdx.x, b = blockIdx.y, tid = threadIdx.x;
  __shared__ float pl[64];
  if (tid < 64) pl[tid] = pooled[b * DDIM + s * 64 + tid];
  __syncthreads();
  float a0 = 0.f, a1 = 0.f;
  const float* wbase = Wm1 + (size_t)(s * 64) * MMD;
#pragma unroll 8
  for (int dd = 0; dd < 64; ++dd) {
    float p = pl[dd];
    a0 += p * wbase[(size_t)dd * MMD + tid];
    a1 += p * wbase[(size_t)dd * MMD + tid + 256];
  }
  atomicAdd(&hidden[b * MMD + tid], a0);
  atomicAdd(&hidden[b * MMD + tid + 256], a1);
}

// ---------------- head stage 2 ----------------
__global__ __launch_bounds__(256) void head2_kernel(
    const float* __restrict__ hidden, const float* __restrict__ bm1,
    const float* __restrict__ Wm2, const float* __restrict__ bm2, float* __restrict__ out) {
  const int b = blockIdx.x, tid = threadIdx.x;
  float part = 0.f;
#pragma unroll
  for (int jj = 0; jj < 2; ++jj) {
    int j = tid + jj * 256;
    part += fmaxf(hidden[b * MMD + j] + bm1[j], 0.f) * Wm2[j];
  }
  __shared__ float red[4];
  int lane = tid & 63, wid = tid >> 6;
  float ssum = wredSum(part);
  if (lane == 0) red[wid] = ssum;
  __syncthreads();
  if (tid == 0) out[b] = red[0] + red[1] + red[2] + red[3] + bm2[0];
}

extern "C" void kernel_launch(void* const* d_in, const int* in_sizes, int n_in,
                              void* d_out, int out_size, void* d_ws, size_t ws_size,
                              hipStream_t stream) {
  const int* cell_types = (const int*)d_in[0];
  const float* distances = (const float*)d_in[1];
  const float* cell_emb = (const float*)d_in[2];
  const float* Kqk = (const float*)d_in[3];
  const float* Kqr = (const float*)d_in[4];
  const float* Kkr = (const float*)d_in[5];
  const float* Vqk = (const float*)d_in[6];
  const float* Vqr = (const float*)d_in[7];
  const float* Vkr = (const float*)d_in[8];
  const float* Wq = (const float*)d_in[9];
  const float* Wk = (const float*)d_in[10];
  const float* Wv = (const float*)d_in[11];
  const float* Wo = (const float*)d_in[12];
  const float* bq = (const float*)d_in[13];
  const float* bk = (const float*)d_in[14];
  const float* bv = (const float*)d_in[15];
  const float* bo = (const float*)d_in[16];
  const float* W1 = (const float*)d_in[17];
  const float* b1 = (const float*)d_in[18];
  const float* W2 = (const float*)d_in[19];
  const float* b2 = (const float*)d_in[20];
  const float* g1 = (const float*)d_in[21];
  const float* be1 = (const float*)d_in[22];
  const float* g2 = (const float*)d_in[23];
  const float* be2 = (const float*)d_in[24];
  const float* Wm1 = (const float*)d_in[25];
  const float* bm1 = (const float*)d_in[26];
  const float* Wm2 = (const float*)d_in[27];
  const float* bm2 = (const float*)d_in[28];

  char* w = (char*)d_ws;
  auto alloc = [&](size_t bytes) { void* p = (void*)w; w += (bytes + 255) & ~(size_t)255; return p; };
  unsigned char* didx = (unsigned char*)alloc(sizeof(unsigned char) * BB * LL * LL);
  float* h    = (float*)alloc(sizeof(float) * BB * LL * DDIM);
  u16* hbf    = (u16*)alloc(sizeof(u16) * BB * LL * DDIM);
  float* h2   = (float*)alloc(sizeof(float) * BB * LL * DDIM);
  u16* h2bf   = (u16*)alloc(sizeof(u16) * BB * LL * DDIM);
  u16* qkvbf  = (u16*)alloc(sizeof(u16) * BB * LL * QKS);
  float* ob   = (float*)alloc(sizeof(float) * BB * LL * DDIM);
  u16* f1bf   = (u16*)alloc(sizeof(u16) * BB * LL * FFD);
  u16* zbf    = (u16*)alloc(sizeof(u16) * BB * LL * DDIM);
  u16* vtbf   = (u16*)alloc(sizeof(u16) * BB * HH * KHD * LL);
  float* qE2  = (float*)alloc(sizeof(float) * BB * HH * LL * NDB);
  u16* kEbf   = (u16*)alloc(sizeof(u16) * (size_t)BB * HH * LL * 16);
  u16* Ebuf   = (u16*)alloc(sizeof(u16) * (size_t)BB * HH * LL * LL);
  float* vbias = (float*)alloc(sizeof(float) * (size_t)BB * HH * LL * KHD);
  float* invs = (float*)alloc(sizeof(float) * (size_t)BB * HH * LL);
  u16* Wqkvt  = (u16*)alloc(sizeof(u16) * (size_t)NLAY * QKS * DDIM);
  u16* Wot    = (u16*)alloc(sizeof(u16) * (size_t)NLAY * DDIM * DDIM);
  u16* W1t    = (u16*)alloc(sizeof(u16) * (size_t)NLAY * FFD * DDIM);
  u16* W2t    = (u16*)alloc(sizeof(u16) * (size_t)NLAY * DDIM * FFD);
  float* bqkv = (float*)alloc(sizeof(float) * NLAY * QKS);
  float* Vsum = (float*)alloc(sizeof(float) * NDB * KHD);
  float* EkrS = (float*)alloc(sizeof(float) * NDB);
  float* pooled = (float*)alloc(sizeof(float) * BB * DDIM);
  float* hidden = (float*)alloc(sizeof(float) * BB * MMD);

  const int Mrows = BB * LL;

  bucketize_kernel<<<(BB * LL * LL / 4 + 255) / 256, 256, 0, stream>>>(distances, didx, BB * LL * LL / 4);
  embed_kernel<<<(BB * LL * DDIM + 255) / 256, 256, 0, stream>>>(cell_types, cell_emb, h, hbf, BB * LL * DDIM);
  prep_kernel<<<1, 512, 0, stream>>>(Vqk, Vqr, Vkr, Kkr, Vsum, EkrS);
  biaspack_kernel<<<(NLAY * QKS + 255) / 256, 256, 0, stream>>>(bq, bk, bv, bqkv);
  hipMemsetAsync(pooled, 0, sizeof(float) * BB * DDIM, stream);
  hipMemsetAsync(hidden, 0, sizeof(float) * BB * MMD, stream);

  for (int lay = 0; lay < NLAY; ++lay) {
    wconv_layer<<<768, 256, 0, stream>>>(
        Wq + (size_t)lay * DDIM * DDIM, Wk + (size_t)lay * DDIM * DDIM,
        Wv + (size_t)lay * DDIM * DDIM, Wo + (size_t)lay * DDIM * DDIM,
        W1 + (size_t)lay * DDIM * FFD, W2 + (size_t)lay * FFD * DDIM,
        Wqkvt + (size_t)lay * QKS * DDIM, Wot + (size_t)lay * DDIM * DDIM,
        W1t + (size_t)lay * FFD * DDIM, W2t + (size_t)lay * DDIM * FFD);
  }

  const int nrel = BB * HH * LL * NDB;

  for (int lay = 0; lay < NLAY; ++lay) {
    // QKV: q/k packed bf16 (q scaled), V written transposed into vtbf (vtrans kernel eliminated)
    gemm_bf16<0><<<dim3((Mrows / 32) * (QKS / 64)), 256, 0, stream>>>(
        hbf, Wqkvt + (size_t)lay * QKS * DDIM, bqkv + (size_t)lay * QKS,
        nullptr, qkvbf, vtbf, Mrows, QKS, DDIM);

    proj_qk_kernel<<<(nrel + 255) / 256, 256, 0, stream>>>(qkvbf, Kqk, Kqr, EkrS, qE2, kEbf);
    attn_exp_kernel<<<dim3(2048), 256, 0, stream>>>(qkvbf, qE2, kEbf, didx, Vsum, Ebuf, vbias, invs);
    attn_pv_kernel<<<dim3(512), 256, 0, stream>>>(Ebuf, vtbf, vbias, invs, zbf);

    gemm_bf16<1><<<dim3((Mrows / 32) * (DDIM / 64)), 256, 0, stream>>>(
        zbf, Wot + (size_t)lay * DDIM * DDIM, bo + (size_t)lay * DDIM, ob, nullptr, nullptr, Mrows, DDIM, DDIM);
    add_ln_kernel<<<Mrows, 256, 0, stream>>>(h, ob, g1 + (size_t)lay * DDIM, be1 + (size_t)lay * DDIM, h2, h2bf);
    gemm_bf16<2><<<dim3((Mrows / 32) * (FFD / 64)), 256, 0, stream>>>(
        h2bf, W1t + (size_t)lay * FFD * DDIM, b1 + (size_t)lay * FFD, nullptr, f1bf, nullptr, Mrows, FFD, DDIM);
    gemm_bf16<3><<<dim3((Mrows / 32) * (DDIM / 64)), 256, 0, stream>>>(
        f1bf, W2t + (size_t)lay * DDIM * FFD, b2 + (size_t)lay * DDIM, ob, nullptr, nullptr, Mrows, DDIM, FFD);
    add_ln_kernel<<<Mrows, 256, 0, stream>>>(h2, ob, g2 + (size_t)lay * DDIM, be2 + (size_t)lay * DDIM, h, hbf);
  }

  pool2_kernel<<<dim3(8, BB), 256, 0, stream>>>(h, pooled);
  head1_kernel<<<dim3(8, BB), 256, 0, stream>>>(pooled, Wm1, hidden);
  head2_kernel<<<BB, 256, 0, stream>>>(hidden, bm1, Wm2, bm2, (float*)d_out);
}

// Round 17
// 976.574 us; speedup vs baseline: 1.1375x; 1.0005x over previous
//
#include <hip/hip_runtime.h>
#include <math.h>

#define NLAY 8
#define BB 4
#define LL 512
#define DDIM 512
#define HH 16
#define KHD 32
#define FFD 2048
#define MMD 512
#define NDB 14
#define QKS 1536
#define SCALEF 0.17677669529663687f

typedef unsigned short u16;
typedef unsigned int u32;
typedef __attribute__((ext_vector_type(8))) short bf16x8;
typedef __attribute__((ext_vector_type(4))) float f32x4;
typedef __attribute__((ext_vector_type(4))) u32 u32x4;

__device__ __forceinline__ u16 f2bf(float f) {
  unsigned u = __builtin_bit_cast(unsigned, f);
  u = (u + 0x7fffu + ((u >> 16) & 1u)) >> 16;
  return (u16)u;
}
__device__ __forceinline__ float bf2f(u16 v) {
  unsigned u = ((unsigned)v) << 16;
  return __builtin_bit_cast(float, u);
}
__device__ __forceinline__ u32 cvt_pk_bf16(float lo, float hi) {
  u32 r;
  asm("v_cvt_pk_bf16_f32 %0, %1, %2" : "=v"(r) : "v"(lo), "v"(hi));
  return r;
}
__device__ __forceinline__ float wredSum(float v) {
#pragma unroll
  for (int o = 32; o > 0; o >>= 1) v += __shfl_down(v, o);
  return v;
}
__device__ __forceinline__ void gload_lds16(const u16* g, u16* l) {
  __builtin_amdgcn_global_load_lds((const __attribute__((address_space(1))) void*)g,
                                   (__attribute__((address_space(3))) void*)l, 16, 0, 0);
}

// ---------------- bucketize -> uint8, [b][l][x] layout ----------------
__global__ void bucketize_kernel(const float* __restrict__ dist, unsigned char* __restrict__ didx, int n) {
  int i = blockIdx.x * 256 + threadIdx.x;
  if (i >= n) return;
  float4 v = ((const float4*)dist)[i];
  float vv[4] = {v.x, v.y, v.z, v.w};
  unsigned char o[4];
#pragma unroll
  for (int j = 0; j < 4; ++j) {
    int c = 0;
#pragma unroll
    for (int s = 1; s <= NDB; ++s) c += (10.0f * (float)s < vv[j]) ? 1 : 0;
    o[j] = (unsigned char)(c > (NDB - 1) ? (NDB - 1) : c);
  }
  *(uchar4*)(didx + i * 4) = *(uchar4*)o;
}

// ---------------- h = cell_emb[cell_types] (f32 + bf16) ----------------
__global__ void embed_kernel(const int* __restrict__ ct, const float* __restrict__ emb,
                             float* __restrict__ h, u16* __restrict__ hbf, int n) {
  int i = blockIdx.x * 256 + threadIdx.x;
  if (i >= n) return;
  int bl = i >> 9, d = i & 511;
  float v = emb[ct[bl] * DDIM + d];
  h[i] = v;
  hbf[i] = f2bf(v);
}

// ---------------- Vsum, EkrS ----------------
__global__ void prep_kernel(const float* __restrict__ Vqk, const float* __restrict__ Vqr,
                            const float* __restrict__ Vkr, const float* __restrict__ Kkr,
                            float* __restrict__ Vsum, float* __restrict__ EkrS) {
  int tid = threadIdx.x;
  if (tid < NDB * KHD) Vsum[tid] = Vqk[tid] + Vqr[tid] + Vkr[tid];
  if (tid < NDB) {
    float s = 0.f;
    for (int kk = 0; kk < KHD; ++kk) s += Kkr[tid * KHD + kk];
    EkrS[tid] = s;
  }
}

// ---------------- packed qkv bias [NLAY][1536] ----------------
__global__ void biaspack_kernel(const float* __restrict__ bq, const float* __restrict__ bk,
                                const float* __restrict__ bv, float* __restrict__ bqkv) {
  int i = blockIdx.x * 256 + threadIdx.x;
  if (i >= NLAY * QKS) return;
  int lay = i / QKS, c = i % QKS;
  float v;
  if (c < 512) v = bq[lay * DDIM + c];
  else if (c < 1024) v = bk[lay * DDIM + c - 512];
  else v = bv[lay * DDIM + c - 1024];
  bqkv[i] = v;
}

// ---------------- weight transpose+convert ----------------
__device__ __forceinline__ void wtconv_tile(const float* __restrict__ src, u16* __restrict__ dst,
                                            int K, int N, int tn, int tk) {
  __shared__ float tl[64][65];
  const int t = threadIdx.x;
#pragma unroll
  for (int p = 0; p < 4; ++p) {
    int k = tk * 64 + p * 16 + (t >> 4);
    int n = tn * 64 + (t & 15) * 4;
    float4 v = *(const float4*)(src + (size_t)k * N + n);
    tl[(t & 15) * 4 + 0][p * 16 + (t >> 4)] = v.x;
    tl[(t & 15) * 4 + 1][p * 16 + (t >> 4)] = v.y;
    tl[(t & 15) * 4 + 2][p * 16 + (t >> 4)] = v.z;
    tl[(t & 15) * 4 + 3][p * 16 + (t >> 4)] = v.w;
  }
  __syncthreads();
  int n = t >> 2, cc = t & 3;
  u16 o[16];
#pragma unroll
  for (int e = 0; e < 16; ++e) o[e] = f2bf(tl[n][cc * 16 + e]);
  u16* dp = dst + (size_t)(tn * 64 + n) * K + tk * 64 + cc * 16;
  *(uint4*)(dp) = *(uint4*)&o[0];
  *(uint4*)(dp + 8) = *(uint4*)&o[8];
}

__global__ __launch_bounds__(256) void wconv_layer(
    const float* __restrict__ Wq, const float* __restrict__ Wk, const float* __restrict__ Wv,
    const float* __restrict__ Wo, const float* __restrict__ W1, const float* __restrict__ W2,
    u16* __restrict__ Wqkvt, u16* __restrict__ Wot, u16* __restrict__ W1t, u16* __restrict__ W2t) {
  int b = blockIdx.x;
  if (b < 64) { wtconv_tile(Wq, Wqkvt, 512, 512, b >> 3, b & 7); return; }
  if (b < 128) { b -= 64; wtconv_tile(Wk, Wqkvt + 512 * 512, 512, 512, b >> 3, b & 7); return; }
  if (b < 192) { b -= 128; wtconv_tile(Wv, Wqkvt + 1024 * 512, 512, 512, b >> 3, b & 7); return; }
  if (b < 256) { b -= 192; wtconv_tile(Wo, Wot, 512, 512, b >> 3, b & 7); return; }
  if (b < 512) { b -= 256; wtconv_tile(W1, W1t, 512, FFD, b >> 3, b & 7); return; }
  b -= 512; wtconv_tile(W2, W2t, FFD, 512, b >> 5, b & 31);
}

// ---------------- bf16 MFMA GEMM: 32x64 tile, BK=64, 4 waves (2x2), XCD y-chunked swizzle ----------------
// TAG 0 = QKV (q/k packed bf16 + V transposed), 1 = O (f32), 2 = FF1 (gelu bf16), 3 = FF2 (f32)
template <int TAG>
__global__ __launch_bounds__(256) void gemm_bf16(
    const u16* __restrict__ A, const u16* __restrict__ Bt, const float* __restrict__ bias,
    float* __restrict__ Cf, u16* __restrict__ Cb, u16* __restrict__ Vt,
    int M, int N, int K) {
  __shared__ u16 As[32 * 64];
  __shared__ u16 Bs[64 * 64];
  const int tid = threadIdx.x, w = tid >> 6, lane = tid & 63;
  const int lr = lane & 15, lg = lane >> 4;
  const int wr = w >> 1, wc = w & 1;
  const int gx = N >> 6;
  const int bi = blockIdx.x;
  const int xcd = bi & 7, rr = bi >> 3;
  const int y = xcd * 8 + rr / gx, x = rr % gx;
  const int row0 = y * 32, col0 = x * 64;
  const int srow = lane >> 3;
  const int aoff = ((lane & 7) ^ srow) * 8;
  const f32x4 z4 = {0.f, 0.f, 0.f, 0.f};
  f32x4 acc[2] = {z4, z4};

  for (int k0 = 0; k0 < K; k0 += 64) {
    gload_lds16(A + (size_t)(row0 + w * 8 + srow) * K + k0 + aoff, As + (w * 8) * 64);
#pragma unroll
    for (int i = 0; i < 2; ++i)
      gload_lds16(Bt + (size_t)(col0 + w * 16 + i * 8 + srow) * K + k0 + aoff,
                  Bs + (w * 16 + i * 8) * 64);
    __syncthreads();
#pragma unroll
    for (int kh = 0; kh < 2; ++kh) {
      bf16x8 a, b[2];
      {
        int r = wr * 16 + lr;
        a = *(const bf16x8*)(As + r * 64 + (((kh * 4 + lg) ^ (r & 7)) << 3));
      }
#pragma unroll
      for (int ni = 0; ni < 2; ++ni) {
        int r = wc * 32 + ni * 16 + lr;
        b[ni] = *(const bf16x8*)(Bs + r * 64 + (((kh * 4 + lg) ^ (r & 7)) << 3));
      }
#pragma unroll
      for (int ni = 0; ni < 2; ++ni)
        acc[ni] = __builtin_amdgcn_mfma_f32_16x16x32_bf16(a, b[ni], acc[ni], 0, 0, 0);
    }
    __syncthreads();
  }
  {
    int r = row0 + wr * 16 + lg * 4;
#pragma unroll
    for (int ni = 0; ni < 2; ++ni) {
      int c = col0 + wc * 32 + ni * 16 + lr;
      float bs = bias[c];
#pragma unroll
      for (int j = 0; j < 4; ++j) {
        float v = acc[ni][j] + bs;
        int rg = r + j;
        size_t idx = (size_t)rg * N + c;
        if (TAG == 0) {
          if (c < 1024) {
            Cb[idx] = f2bf(c < 512 ? v * SCALEF : v);
          } else {
            int cc = c - 1024, hh = cc >> 5, kh2 = cc & 31;
            int bb = rg >> 9, l = rg & 511;
            Vt[(((size_t)(bb * HH + hh)) * KHD + kh2) * LL + l] = f2bf(v);
          }
        } else if (TAG == 2) {
          v = 0.5f * v * (1.0f + erff(v * 0.70710678118654752f));
          Cb[idx] = f2bf(v);
        } else {
          Cf[idx] = v;
        }
      }
    }
  }
}

// ---------------- merged rel projections: qE2 (f32) + kEbf (bf16 [bhl][16]) ----------------
__global__ void proj_qk_kernel(const u16* __restrict__ qkv, const float* __restrict__ Kqk,
                               const float* __restrict__ Kqr, const float* __restrict__ ekrs,
                               float* __restrict__ qE2, u16* __restrict__ kEbf) {
  int idx = blockIdx.x * 256 + threadIdx.x;
  if (idx >= BB * HH * LL * NDB) return;
  int d = idx % NDB;
  int rest = idx / NDB;
  int l = rest & (LL - 1);
  int bh = rest >> 9;
  int h = bh & (HH - 1);
  int b = bh >> 4;
  const u16* qr_ = qkv + ((size_t)(b * LL + l)) * QKS + h * KHD;
  const u16* kr_ = qr_ + 512;
  const float* kq = Kqk + d * KHD;
  const float* kk2 = Kqr + d * KHD;
  float sq = 0.f, sk = 0.f;
#pragma unroll
  for (int kk = 0; kk < KHD; ++kk) {
    sq += bf2f(qr_[kk]) * kq[kk];
    sk += bf2f(kr_[kk]) * kk2[kk];
  }
  qE2[idx] = sq;
  kEbf[(size_t)rest * 16 + d] = f2bf(sk * SCALEF + SCALEF * ekrs[d]);
}

// ---------------- attn A: batched loads; E stored CHUNK-MAJOR E2[(b,h)][x0/32][l][32] ----------------
// Chunk-major store: a wave's per-chunk write = 16 consecutive 64B rows = 1KB contiguous block
// (was 16 rows x 64B at 1KB stride = half-line scatter). attn_pv reads the same blocks.
__global__ __launch_bounds__(256) void attn_exp_kernel(
    const u16* __restrict__ qkv, const float* __restrict__ qE2, const u16* __restrict__ kEbf,
    const unsigned char* __restrict__ didx, const float* __restrict__ Vsum,
    u16* __restrict__ E, float* __restrict__ vbias, float* __restrict__ invs) {
  const int i = blockIdx.x;
  const int j = i >> 3;
  const int g = (i & 7) * 8 + (j >> 5);
  const int qr = j & 31;
  const int h = g & 15, b = g >> 4;
  const int tid = threadIdx.x, lane = tid & 63, w = tid >> 6;
  const int lr = lane & 15, lg = lane >> 4;
  const int row0 = qr * 16;

  __shared__ u16 kEs[LL][18];
  __shared__ float qEs[16][17];
  __shared__ float hist[4][64][17];

  {
    const u32* gs = (const u32*)(kEbf + (((size_t)(b * HH + h)) * LL) * 16);
    u32* ls = (u32*)(&kEs[0][0]);
#pragma unroll
    for (int t = 0; t < 16; ++t) {
      int idx = t * 256 + tid;
      int r = idx >> 3, c = idx & 7;
      ls[r * 9 + c] = gs[idx];
    }
  }
  if (tid < 224) {
    int r = tid / 14, d = tid % 14;
    qEs[r][d] = qE2[(((size_t)(b * HH + h)) * LL + row0 + r) * NDB + d];
  }
  {
    float* hf = &hist[0][0][0];
#pragma unroll
    for (int t = 0; t < 17; ++t) hf[t * 256 + tid] = 0.f;
  }

  const bf16x8 aQ = *(const bf16x8*)(qkv + ((size_t)(b * LL + row0 + lr)) * QKS + h * KHD + lg * 8);

  __syncthreads();

  const f32x4 zero4 = {0.f, 0.f, 0.f, 0.f};
  const int keyA = 8 * (lr >> 2) + (lr & 3);
  const u16* kbase = qkv + (size_t)b * LL * QKS + 512 + h * KHD + lg * 8;
  const unsigned char* drow = didx + ((size_t)(b * LL) + row0 + lr) * LL + 8 * lg;
  // chunk-major E: base for this (b,h); per-chunk offset = (w*4+ct)*LL*32
  u16* Ebh = E + (((size_t)(b * HH + h)) * 16) * (LL * 32) + (size_t)(row0 + lr) * 32 + 8 * lg;
  float* hlane = &hist[w][lane][0];

  bf16x8 kA[4], kB[4];
  uint2 dv[4];
#pragma unroll
  for (int ct = 0; ct < 4; ++ct) {
    const int x0 = w * 128 + ct * 32;
    kA[ct] = *(const bf16x8*)(kbase + (size_t)(x0 + keyA) * QKS);
    kB[ct] = *(const bf16x8*)(kbase + (size_t)(x0 + keyA + 4) * QKS);
    dv[ct] = *(const uint2*)(drow + x0);
  }
  __builtin_amdgcn_sched_barrier(0);   // 12 loads stay in flight

#pragma unroll
  for (int ct = 0; ct < 4; ++ct) {
    const int x0 = w * 128 + ct * 32;
    f32x4 sA = __builtin_amdgcn_mfma_f32_16x16x32_bf16(kA[ct], aQ, zero4, 0, 0, 0);
    f32x4 sB = __builtin_amdgcn_mfma_f32_16x16x32_bf16(kB[ct], aQ, zero4, 0, 0, 0);
    float pA[4], pB[4];
#pragma unroll
    for (int q = 0; q < 4; ++q) {
      const int da = (dv[ct].x >> (8 * q)) & 0xff;
      const int db = (dv[ct].y >> (8 * q)) & 0xff;
      pA[q] = __expf(sA[q] + qEs[lr][da] + bf2f(kEs[x0 + 8 * lg + q][da]));
      pB[q] = __expf(sB[q] + qEs[lr][db] + bf2f(kEs[x0 + 8 * lg + 4 + q][db]));
      hlane[da] += pA[q];
      hlane[db] += pB[q];
    }
    u32x4 pw;
    pw[0] = cvt_pk_bf16(pA[0], pA[1]);
    pw[1] = cvt_pk_bf16(pA[2], pA[3]);
    pw[2] = cvt_pk_bf16(pB[0], pB[1]);
    pw[3] = cvt_pk_bf16(pB[2], pB[3]);
    *(u32x4*)(Ebh + (size_t)(w * 4 + ct) * (LL * 32)) = pw;  // 1KB-contiguous per wave-chunk
  }

  __syncthreads();

  const int r = tid >> 4, c = tid & 15;
  float ht[NDB];
  float rsum = 0.f;
#pragma unroll
  for (int d = 0; d < NDB; ++d) {
    float a = 0.f;
#pragma unroll
    for (int ww = 0; ww < 4; ++ww)
#pragma unroll
      for (int gg = 0; gg < 4; ++gg) a += hist[ww][r + 16 * gg][d];
    ht[d] = a;
    rsum += a;
  }
  float vb_0 = 0.f, vb_1 = 0.f;
#pragma unroll
  for (int d = 0; d < NDB; ++d) {
    vb_0 += ht[d] * Vsum[d * KHD + c];
    vb_1 += ht[d] * Vsum[d * KHD + 16 + c];
  }
  const size_t rowi = (((size_t)(b * HH + h)) * LL) + row0 + r;
  vbias[rowi * KHD + c] = vb_0;
  vbias[rowi * KHD + 16 + c] = vb_1;
  if (c == 0) invs[rowi] = 1.0f / rsum;
}

// ---------------- attn B: z = (E @ V^T + vbias) * inv, chunk-major E reads ----------------
__global__ __launch_bounds__(256) void attn_pv_kernel(
    const u16* __restrict__ E, const u16* __restrict__ vtbf,
    const float* __restrict__ vbias, const float* __restrict__ invs,
    u16* __restrict__ z) {
  const int i = blockIdx.x;
  const int j = i >> 3;
  const int g = (i & 7) * 8 + (j >> 3);
  const int qt = j & 7;
  const int h = g & 15, b = g >> 4;
  const int tid = threadIdx.x, lane = tid & 63, w = tid >> 6;
  const int lr = lane & 15, lg = lane >> 4;
  const int row0 = qt * 64 + w * 16;

  f32x4 o0 = {0.f, 0.f, 0.f, 0.f}, o1 = {0.f, 0.f, 0.f, 0.f};
  const u16* Ebh = E + (((size_t)(b * HH + h)) * 16) * (LL * 32) + (size_t)(row0 + lr) * 32 + lg * 8;
  const u16* vbase = vtbf + ((size_t)(b * HH + h) * KHD) * LL + lg * 8;

#pragma unroll 4
  for (int ct = 0; ct < 16; ++ct) {
    const int x0 = ct * 32;
    bf16x8 aE = *(const bf16x8*)(Ebh + (size_t)ct * (LL * 32));
    bf16x8 vb0 = *(const bf16x8*)(vbase + (size_t)lr * LL + x0);
    bf16x8 vb1 = *(const bf16x8*)(vbase + (size_t)(16 + lr) * LL + x0);
    o0 = __builtin_amdgcn_mfma_f32_16x16x32_bf16(aE, vb0, o0, 0, 0, 0);
    o1 = __builtin_amdgcn_mfma_f32_16x16x32_bf16(aE, vb1, o1, 0, 0, 0);
  }

#pragma unroll
  for (int q = 0; q < 4; ++q) {
    const int rl = lg * 4 + q;
    const size_t rowi = (((size_t)(b * HH + h)) * LL) + row0 + rl;
    const float inv = invs[rowi];
    const float v0 = vbias[rowi * KHD + lr];
    const float v1 = vbias[rowi * KHD + 16 + lr];
    const size_t orow = ((size_t)(b * LL + row0 + rl)) * DDIM + h * KHD;
    z[orow + lr] = f2bf((o0[q] + v0) * inv);
    z[orow + 16 + lr] = f2bf((o1[q] + v1) * inv);
  }
}

// ---------------- out = LN(X + Y), f32 + bf16 ----------------
__global__ __launch_bounds__(256) void add_ln_kernel(
    const float* __restrict__ X, const float* __restrict__ Y,
    const float* __restrict__ g, const float* __restrict__ be,
    float* __restrict__ out, u16* __restrict__ outb) {
  const int row = blockIdx.x, tid = threadIdx.x;
  const int lane = tid & 63, wid = tid >> 6;
  __shared__ float red[4];
  const size_t base = (size_t)row * DDIM;
  float x0 = X[base + tid] + Y[base + tid];
  float x1 = X[base + tid + 256] + Y[base + tid + 256];
  float s = wredSum(x0 + x1);
  if (lane == 0) red[wid] = s;
  __syncthreads();
  float mu = (red[0] + red[1] + red[2] + red[3]) * (1.0f / DDIM);
  __syncthreads();
  float d0 = x0 - mu, d1 = x1 - mu;
  float vs = wredSum(d0 * d0 + d1 * d1);
  if (lane == 0) red[wid] = vs;
  __syncthreads();
  float var = (red[0] + red[1] + red[2] + red[3]) * (1.0f / DDIM);
  float inv = rsqrtf(var + 1e-5f);
  float r0 = d0 * inv * g[tid] + be[tid];
  float r1 = d1 * inv * g[tid + 256] + be[tid + 256];
  out[base + tid] = r0;
  out[base + tid + 256] = r1;
  outb[base + tid] = f2bf(r0);
  outb[base + tid + 256] = f2bf(r1);
}

// ---------------- pool v2 ----------------
__global__ __launch_bounds__(256) void pool2_kernel(const float* __restrict__ h, float* __restrict__ pooled) {
  const int s = blockIdx.x, b = blockIdx.y, tid = threadIdx.x;
  float a0 = 0.f, a1 = 0.f;
  const float* base = h + ((size_t)(b * LL) + s * 64) * DDIM;
#pragma unroll 4
  for (int l = 0; l < 64; ++l) {
    a0 += base[(size_t)l * DDIM + tid];
    a1 += base[(size_t)l * DDIM + tid + 256];
  }
  atomicAdd(&pooled[b * DDIM + tid], a0);
  atomicAdd(&pooled[b * DDIM + tid + 256], a1);
}

// ---------------- head stage 1 ----------------
__global__ __launch_bounds__(256) void head1_kernel(
    const float* __restrict__ pooled, const float* __restrict__ Wm1, float* __restrict__ hidden) {
  const int s = blockIdx.x, b = blockIdx.y, tid = threadIdx.x;
  __shared__ float pl[64];
  if (tid < 64) pl[tid] = pooled[b * DDIM + s * 64 + tid];
  __syncthreads();
  float a0 = 0.f, a1 = 0.f;
  const float* wbase = Wm1 + (size_t)(s * 64) * MMD;
#pragma unroll 8
  for (int dd = 0; dd < 64; ++dd) {
    float p = pl[dd];
    a0 += p * wbase[(size_t)dd * MMD + tid];
    a1 += p * wbase[(size_t)dd * MMD + tid + 256];
  }
  atomicAdd(&hidden[b * MMD + tid], a0);
  atomicAdd(&hidden[b * MMD + tid + 256], a1);
}

// ---------------- head stage 2 ----------------
__global__ __launch_bounds__(256) void head2_kernel(
    const float* __restrict__ hidden, const float* __restrict__ bm1,
    const float* __restrict__ Wm2, const float* __restrict__ bm2, float* __restrict__ out) {
  const int b = blockIdx.x, tid = threadIdx.x;
  float part = 0.f;
#pragma unroll
  for (int jj = 0; jj < 2; ++jj) {
    int j = tid + jj * 256;
    part += fmaxf(hidden[b * MMD + j] + bm1[j], 0.f) * Wm2[j];
  }
  __shared__ float red[4];
  int lane = tid & 63, wid = tid >> 6;
  float ssum = wredSum(part);
  if (lane == 0) red[wid] = ssum;
  __syncthreads();
  if (tid == 0) out[b] = red[0] + red[1] + red[2] + red[3] + bm2[0];
}

extern "C" void kernel_launch(void* const* d_in, const int* in_sizes, int n_in,
                              void* d_out, int out_size, void* d_ws, size_t ws_size,
                              hipStream_t stream) {
  const int* cell_types = (const int*)d_in[0];
  const float* distances = (const float*)d_in[1];
  const float* cell_emb = (const float*)d_in[2];
  const float* Kqk = (const float*)d_in[3];
  const float* Kqr = (const float*)d_in[4];
  const float* Kkr = (const float*)d_in[5];
  const float* Vqk = (const float*)d_in[6];
  const float* Vqr = (const float*)d_in[7];
  const float* Vkr = (const float*)d_in[8];
  const float* Wq = (const float*)d_in[9];
  const float* Wk = (const float*)d_in[10];
  const float* Wv = (const float*)d_in[11];
  const float* Wo = (const float*)d_in[12];
  const float* bq = (const float*)d_in[13];
  const float* bk = (const float*)d_in[14];
  const float* bv = (const float*)d_in[15];
  const float* bo = (const float*)d_in[16];
  const float* W1 = (const float*)d_in[17];
  const float* b1 = (const float*)d_in[18];
  const float* W2 = (const float*)d_in[19];
  const float* b2 = (const float*)d_in[20];
  const float* g1 = (const float*)d_in[21];
  const float* be1 = (const float*)d_in[22];
  const float* g2 = (const float*)d_in[23];
  const float* be2 = (const float*)d_in[24];
  const float* Wm1 = (const float*)d_in[25];
  const float* bm1 = (const float*)d_in[26];
  const float* Wm2 = (const float*)d_in[27];
  const float* bm2 = (const float*)d_in[28];

  char* w = (char*)d_ws;
  auto alloc = [&](size_t bytes) { void* p = (void*)w; w += (bytes + 255) & ~(size_t)255; return p; };
  unsigned char* didx = (unsigned char*)alloc(sizeof(unsigned char) * BB * LL * LL);
  float* h    = (float*)alloc(sizeof(float) * BB * LL * DDIM);
  u16* hbf    = (u16*)alloc(sizeof(u16) * BB * LL * DDIM);
  float* h2   = (float*)alloc(sizeof(float) * BB * LL * DDIM);
  u16* h2bf   = (u16*)alloc(sizeof(u16) * BB * LL * DDIM);
  u16* qkvbf  = (u16*)alloc(sizeof(u16) * BB * LL * QKS);
  float* ob   = (float*)alloc(sizeof(float) * BB * LL * DDIM);
  u16* f1bf   = (u16*)alloc(sizeof(u16) * BB * LL * FFD);
  u16* zbf    = (u16*)alloc(sizeof(u16) * BB * LL * DDIM);
  u16* vtbf   = (u16*)alloc(sizeof(u16) * BB * HH * KHD * LL);
  float* qE2  = (float*)alloc(sizeof(float) * BB * HH * LL * NDB);
  u16* kEbf   = (u16*)alloc(sizeof(u16) * (size_t)BB * HH * LL * 16);
  u16* Ebuf   = (u16*)alloc(sizeof(u16) * (size_t)BB * HH * LL * LL);
  float* vbias = (float*)alloc(sizeof(float) * (size_t)BB * HH * LL * KHD);
  float* invs = (float*)alloc(sizeof(float) * (size_t)BB * HH * LL);
  u16* Wqkvt  = (u16*)alloc(sizeof(u16) * (size_t)NLAY * QKS * DDIM);
  u16* Wot    = (u16*)alloc(sizeof(u16) * (size_t)NLAY * DDIM * DDIM);
  u16* W1t    = (u16*)alloc(sizeof(u16) * (size_t)NLAY * FFD * DDIM);
  u16* W2t    = (u16*)alloc(sizeof(u16) * (size_t)NLAY * DDIM * FFD);
  float* bqkv = (float*)alloc(sizeof(float) * NLAY * QKS);
  float* Vsum = (float*)alloc(sizeof(float) * NDB * KHD);
  float* EkrS = (float*)alloc(sizeof(float) * NDB);
  float* pooled = (float*)alloc(sizeof(float) * BB * DDIM);
  float* hidden = (float*)alloc(sizeof(float) * BB * MMD);

  const int Mrows = BB * LL;

  bucketize_kernel<<<(BB * LL * LL / 4 + 255) / 256, 256, 0, stream>>>(distances, didx, BB * LL * LL / 4);
  embed_kernel<<<(BB * LL * DDIM + 255) / 256, 256, 0, stream>>>(cell_types, cell_emb, h, hbf, BB * LL * DDIM);
  prep_kernel<<<1, 512, 0, stream>>>(Vqk, Vqr, Vkr, Kkr, Vsum, EkrS);
  biaspack_kernel<<<(NLAY * QKS + 255) / 256, 256, 0, stream>>>(bq, bk, bv, bqkv);
  hipMemsetAsync(pooled, 0, sizeof(float) * BB * DDIM, stream);
  hipMemsetAsync(hidden, 0, sizeof(float) * BB * MMD, stream);

  for (int lay = 0; lay < NLAY; ++lay) {
    wconv_layer<<<768, 256, 0, stream>>>(
        Wq + (size_t)lay * DDIM * DDIM, Wk + (size_t)lay * DDIM * DDIM,
        Wv + (size_t)lay * DDIM * DDIM, Wo + (size_t)lay * DDIM * DDIM,
        W1 + (size_t)lay * DDIM * FFD, W2 + (size_t)lay * FFD * DDIM,
        Wqkvt + (size_t)lay * QKS * DDIM, Wot + (size_t)lay * DDIM * DDIM,
        W1t + (size_t)lay * FFD * DDIM, W2t + (size_t)lay * DDIM * FFD);
  }

  const int nrel = BB * HH * LL * NDB;

  for (int lay = 0; lay < NLAY; ++lay) {
    gemm_bf16<0><<<dim3((Mrows / 32) * (QKS / 64)), 256, 0, stream>>>(
        hbf, Wqkvt + (size_t)lay * QKS * DDIM, bqkv + (size_t)lay * QKS,
        nullptr, qkvbf, vtbf, Mrows, QKS, DDIM);

    proj_qk_kernel<<<(nrel + 255) / 256, 256, 0, stream>>>(qkvbf, Kqk, Kqr, EkrS, qE2, kEbf);
    attn_exp_kernel<<<dim3(2048), 256, 0, stream>>>(qkvbf, qE2, kEbf, didx, Vsum, Ebuf, vbias, invs);
    attn_pv_kernel<<<dim3(512), 256, 0, stream>>>(Ebuf, vtbf, vbias, invs, zbf);

    gemm_bf16<1><<<dim3((Mrows / 32) * (DDIM / 64)), 256, 0, stream>>>(
        zbf, Wot + (size_t)lay * DDIM * DDIM, bo + (size_t)lay * DDIM, ob, nullptr, nullptr, Mrows, DDIM, DDIM);
    add_ln_kernel<<<Mrows, 256, 0, stream>>>(h, ob, g1 + (size_t)lay * DDIM, be1 + (size_t)lay * DDIM, h2, h2bf);
    gemm_bf16<2><<<dim3((Mrows / 32) * (FFD / 64)), 256, 0, stream>>>(
        h2bf, W1t + (size_t)lay * FFD * DDIM, b1 + (size_t)lay * FFD, nullptr, f1bf, nullptr, Mrows, FFD, DDIM);
    gemm_bf16<3><<<dim3((Mrows / 32) * (DDIM / 64)), 256, 0, stream>>>(
        f1bf, W2t + (size_t)lay * DDIM * FFD, b2 + (size_t)lay * DDIM, ob, nullptr, nullptr, Mrows, DDIM, FFD);
    add_ln_kernel<<<Mrows, 256, 0, stream>>>(h2, ob, g2 + (size_t)lay * DDIM, be2 + (size_t)lay * DDIM, h, hbf);
  }

  pool2_kernel<<<dim3(8, BB), 256, 0, stream>>>(h, pooled);
  head1_kernel<<<dim3(8, BB), 256, 0, stream>>>(pooled, Wm1, hidden);
  head2_kernel<<<BB, 256, 0, stream>>>(hidden, bm1, Wm2, bm2, (float*)d_out);
}

// Round 18
// 968.473 us; speedup vs baseline: 1.1470x; 1.0084x over previous
//
#include <hip/hip_runtime.h>
#include <math.h>

#define NLAY 8
#define BB 4
#define LL 512
#define DDIM 512
#define HH 16
#define KHD 32
#define FFD 2048
#define MMD 512
#define NDB 14
#define QKS 1536
#define SCALEF 0.17677669529663687f

typedef unsigned short u16;
typedef unsigned int u32;
typedef __attribute__((ext_vector_type(8))) short bf16x8;
typedef __attribute__((ext_vector_type(4))) float f32x4;
typedef __attribute__((ext_vector_type(4))) u32 u32x4;

__device__ __forceinline__ u16 f2bf(float f) {
  unsigned u = __builtin_bit_cast(unsigned, f);
  u = (u + 0x7fffu + ((u >> 16) & 1u)) >> 16;
  return (u16)u;
}
__device__ __forceinline__ float bf2f(u16 v) {
  unsigned u = ((unsigned)v) << 16;
  return __builtin_bit_cast(float, u);
}
__device__ __forceinline__ u32 cvt_pk_bf16(float lo, float hi) {
  u32 r;
  asm("v_cvt_pk_bf16_f32 %0, %1, %2" : "=v"(r) : "v"(lo), "v"(hi));
  return r;
}
__device__ __forceinline__ float wredSum(float v) {
#pragma unroll
  for (int o = 32; o > 0; o >>= 1) v += __shfl_down(v, o);
  return v;
}
__device__ __forceinline__ void gload_lds16(const u16* g, u16* l) {
  __builtin_amdgcn_global_load_lds((const __attribute__((address_space(1))) void*)g,
                                   (__attribute__((address_space(3))) void*)l, 16, 0, 0);
}

// ---------------- bucketize -> uint8, [b][l][x] layout ----------------
__global__ void bucketize_kernel(const float* __restrict__ dist, unsigned char* __restrict__ didx, int n) {
  int i = blockIdx.x * 256 + threadIdx.x;
  if (i >= n) return;
  float4 v = ((const float4*)dist)[i];
  float vv[4] = {v.x, v.y, v.z, v.w};
  unsigned char o[4];
#pragma unroll
  for (int j = 0; j < 4; ++j) {
    int c = 0;
#pragma unroll
    for (int s = 1; s <= NDB; ++s) c += (10.0f * (float)s < vv[j]) ? 1 : 0;
    o[j] = (unsigned char)(c > (NDB - 1) ? (NDB - 1) : c);
  }
  *(uchar4*)(didx + i * 4) = *(uchar4*)o;
}

// ---------------- h = cell_emb[cell_types] (f32 + bf16) ----------------
__global__ void embed_kernel(const int* __restrict__ ct, const float* __restrict__ emb,
                             float* __restrict__ h, u16* __restrict__ hbf, int n) {
  int i = blockIdx.x * 256 + threadIdx.x;
  if (i >= n) return;
  int bl = i >> 9, d = i & 511;
  float v = emb[ct[bl] * DDIM + d];
  h[i] = v;
  hbf[i] = f2bf(v);
}

// ---------------- Vsum, EkrS ----------------
__global__ void prep_kernel(const float* __restrict__ Vqk, const float* __restrict__ Vqr,
                            const float* __restrict__ Vkr, const float* __restrict__ Kkr,
                            float* __restrict__ Vsum, float* __restrict__ EkrS) {
  int tid = threadIdx.x;
  if (tid < NDB * KHD) Vsum[tid] = Vqk[tid] + Vqr[tid] + Vkr[tid];
  if (tid < NDB) {
    float s = 0.f;
    for (int kk = 0; kk < KHD; ++kk) s += Kkr[tid * KHD + kk];
    EkrS[tid] = s;
  }
}

// ---------------- packed qkv bias [NLAY][1536] ----------------
__global__ void biaspack_kernel(const float* __restrict__ bq, const float* __restrict__ bk,
                                const float* __restrict__ bv, float* __restrict__ bqkv) {
  int i = blockIdx.x * 256 + threadIdx.x;
  if (i >= NLAY * QKS) return;
  int lay = i / QKS, c = i % QKS;
  float v;
  if (c < 512) v = bq[lay * DDIM + c];
  else if (c < 1024) v = bk[lay * DDIM + c - 512];
  else v = bv[lay * DDIM + c - 1024];
  bqkv[i] = v;
}

// ---------------- weight transpose+convert ----------------
__device__ __forceinline__ void wtconv_tile(const float* __restrict__ src, u16* __restrict__ dst,
                                            int K, int N, int tn, int tk) {
  __shared__ float tl[64][65];
  const int t = threadIdx.x;
#pragma unroll
  for (int p = 0; p < 4; ++p) {
    int k = tk * 64 + p * 16 + (t >> 4);
    int n = tn * 64 + (t & 15) * 4;
    float4 v = *(const float4*)(src + (size_t)k * N + n);
    tl[(t & 15) * 4 + 0][p * 16 + (t >> 4)] = v.x;
    tl[(t & 15) * 4 + 1][p * 16 + (t >> 4)] = v.y;
    tl[(t & 15) * 4 + 2][p * 16 + (t >> 4)] = v.z;
    tl[(t & 15) * 4 + 3][p * 16 + (t >> 4)] = v.w;
  }
  __syncthreads();
  int n = t >> 2, cc = t & 3;
  u16 o[16];
#pragma unroll
  for (int e = 0; e < 16; ++e) o[e] = f2bf(tl[n][cc * 16 + e]);
  u16* dp = dst + (size_t)(tn * 64 + n) * K + tk * 64 + cc * 16;
  *(uint4*)(dp) = *(uint4*)&o[0];
  *(uint4*)(dp + 8) = *(uint4*)&o[8];
}

__global__ __launch_bounds__(256) void wconv_layer(
    const float* __restrict__ Wq, const float* __restrict__ Wk, const float* __restrict__ Wv,
    const float* __restrict__ Wo, const float* __restrict__ W1, const float* __restrict__ W2,
    u16* __restrict__ Wqkvt, u16* __restrict__ Wot, u16* __restrict__ W1t, u16* __restrict__ W2t) {
  int b = blockIdx.x;
  if (b < 64) { wtconv_tile(Wq, Wqkvt, 512, 512, b >> 3, b & 7); return; }
  if (b < 128) { b -= 64; wtconv_tile(Wk, Wqkvt + 512 * 512, 512, 512, b >> 3, b & 7); return; }
  if (b < 192) { b -= 128; wtconv_tile(Wv, Wqkvt + 1024 * 512, 512, 512, b >> 3, b & 7); return; }
  if (b < 256) { b -= 192; wtconv_tile(Wo, Wot, 512, 512, b >> 3, b & 7); return; }
  if (b < 512) { b -= 256; wtconv_tile(W1, W1t, 512, FFD, b >> 3, b & 7); return; }
  b -= 512; wtconv_tile(W2, W2t, FFD, 512, b >> 5, b & 31);
}

// ---------------- bf16 MFMA GEMM 32x64 (O=1, FF2=3) ----------------
template <int TAG>
__global__ __launch_bounds__(256) void gemm_bf16(
    const u16* __restrict__ A, const u16* __restrict__ Bt, const float* __restrict__ bias,
    float* __restrict__ Cf, u16* __restrict__ Cb, u16* __restrict__ Vt,
    int M, int N, int K) {
  __shared__ u16 As[32 * 64];
  __shared__ u16 Bs[64 * 64];
  const int tid = threadIdx.x, w = tid >> 6, lane = tid & 63;
  const int lr = lane & 15, lg = lane >> 4;
  const int wr = w >> 1, wc = w & 1;
  const int gx = N >> 6;
  const int bi = blockIdx.x;
  const int xcd = bi & 7, rr = bi >> 3;
  const int y = xcd * 8 + rr / gx, x = rr % gx;
  const int row0 = y * 32, col0 = x * 64;
  const int srow = lane >> 3;
  const int aoff = ((lane & 7) ^ srow) * 8;
  const f32x4 z4 = {0.f, 0.f, 0.f, 0.f};
  f32x4 acc[2] = {z4, z4};

  for (int k0 = 0; k0 < K; k0 += 64) {
    gload_lds16(A + (size_t)(row0 + w * 8 + srow) * K + k0 + aoff, As + (w * 8) * 64);
#pragma unroll
    for (int i = 0; i < 2; ++i)
      gload_lds16(Bt + (size_t)(col0 + w * 16 + i * 8 + srow) * K + k0 + aoff,
                  Bs + (w * 16 + i * 8) * 64);
    __syncthreads();
#pragma unroll
    for (int kh = 0; kh < 2; ++kh) {
      bf16x8 a, b[2];
      {
        int r = wr * 16 + lr;
        a = *(const bf16x8*)(As + r * 64 + (((kh * 4 + lg) ^ (r & 7)) << 3));
      }
#pragma unroll
      for (int ni = 0; ni < 2; ++ni) {
        int r = wc * 32 + ni * 16 + lr;
        b[ni] = *(const bf16x8*)(Bs + r * 64 + (((kh * 4 + lg) ^ (r & 7)) << 3));
      }
#pragma unroll
      for (int ni = 0; ni < 2; ++ni)
        acc[ni] = __builtin_amdgcn_mfma_f32_16x16x32_bf16(a, b[ni], acc[ni], 0, 0, 0);
    }
    __syncthreads();
  }
  {
    int r = row0 + wr * 16 + lg * 4;
#pragma unroll
    for (int ni = 0; ni < 2; ++ni) {
      int c = col0 + wc * 32 + ni * 16 + lr;
      float bs = bias[c];
#pragma unroll
      for (int j = 0; j < 4; ++j) {
        float v = acc[ni][j] + bs;
        size_t idx = (size_t)(r + j) * N + c;
        Cf[idx] = v;  // TAG 1/3: f32 out
      }
    }
  }
}

// ---------------- bf16 MFMA GEMM 64x64 (QKV=0, FF1=2): 8 MFMA/wave per K-step ----------------
template <int TAG>
__global__ __launch_bounds__(256) void gemm64_bf16(
    const u16* __restrict__ A, const u16* __restrict__ Bt, const float* __restrict__ bias,
    float* __restrict__ Cf, u16* __restrict__ Cb, u16* __restrict__ Vt,
    int M, int N, int K) {
  __shared__ u16 As[64 * 64];
  __shared__ u16 Bs[64 * 64];
  const int tid = threadIdx.x, w = tid >> 6, lane = tid & 63;
  const int lr = lane & 15, lg = lane >> 4;
  const int wr = w >> 1, wc = w & 1;
  const int gx = N >> 6;
  const int bi = blockIdx.x;
  const int xcd = bi & 7, rr = bi >> 3;
  const int ypx = M >> 9;                       // (M/64)/8 rows per XCD; M=2048 -> 4
  const int y = xcd * ypx + rr / gx, x = rr % gx;
  const int row0 = y * 64, col0 = x * 64;
  const int srow = lane >> 3;
  const int aoff = ((lane & 7) ^ srow) * 8;
  const f32x4 z4 = {0.f, 0.f, 0.f, 0.f};
  f32x4 acc[2][2] = {{z4, z4}, {z4, z4}};

  for (int k0 = 0; k0 < K; k0 += 64) {
#pragma unroll
    for (int i = 0; i < 2; ++i) {
      gload_lds16(A + (size_t)(row0 + w * 16 + i * 8 + srow) * K + k0 + aoff,
                  As + (w * 16 + i * 8) * 64);
      gload_lds16(Bt + (size_t)(col0 + w * 16 + i * 8 + srow) * K + k0 + aoff,
                  Bs + (w * 16 + i * 8) * 64);
    }
    __syncthreads();
#pragma unroll
    for (int kh = 0; kh < 2; ++kh) {
      bf16x8 a[2], b[2];
#pragma unroll
      for (int mi = 0; mi < 2; ++mi) {
        int r = wr * 32 + mi * 16 + lr;
        a[mi] = *(const bf16x8*)(As + r * 64 + (((kh * 4 + lg) ^ (r & 7)) << 3));
      }
#pragma unroll
      for (int ni = 0; ni < 2; ++ni) {
        int r = wc * 32 + ni * 16 + lr;
        b[ni] = *(const bf16x8*)(Bs + r * 64 + (((kh * 4 + lg) ^ (r & 7)) << 3));
      }
#pragma unroll
      for (int mi = 0; mi < 2; ++mi)
#pragma unroll
        for (int ni = 0; ni < 2; ++ni)
          acc[mi][ni] = __builtin_amdgcn_mfma_f32_16x16x32_bf16(a[mi], b[ni], acc[mi][ni], 0, 0, 0);
    }
    __syncthreads();
  }
#pragma unroll
  for (int mi = 0; mi < 2; ++mi) {
    int r = row0 + wr * 32 + mi * 16 + lg * 4;
#pragma unroll
    for (int ni = 0; ni < 2; ++ni) {
      int c = col0 + wc * 32 + ni * 16 + lr;
      float bs = bias[c];
#pragma unroll
      for (int j = 0; j < 4; ++j) {
        float v = acc[mi][ni][j] + bs;
        int rg = r + j;
        size_t idx = (size_t)rg * N + c;
        if (TAG == 0) {
          if (c < 1024) {
            Cb[idx] = f2bf(c < 512 ? v * SCALEF : v);
          } else {
            int cc = c - 1024, hh = cc >> 5, kh2 = cc & 31;
            int bb = rg >> 9, l = rg & 511;
            Vt[(((size_t)(bb * HH + hh)) * KHD + kh2) * LL + l] = f2bf(v);
          }
        } else {  // TAG 2: FF1 gelu -> bf16
          v = 0.5f * v * (1.0f + erff(v * 0.70710678118654752f));
          Cb[idx] = f2bf(v);
        }
      }
    }
  }
}

// ---------------- merged rel projections: qE2 (f32) + kEbf (bf16 [bhl][16]) ----------------
__global__ void proj_qk_kernel(const u16* __restrict__ qkv, const float* __restrict__ Kqk,
                               const float* __restrict__ Kqr, const float* __restrict__ ekrs,
                               float* __restrict__ qE2, u16* __restrict__ kEbf) {
  int idx = blockIdx.x * 256 + threadIdx.x;
  if (idx >= BB * HH * LL * NDB) return;
  int d = idx % NDB;
  int rest = idx / NDB;
  int l = rest & (LL - 1);
  int bh = rest >> 9;
  int h = bh & (HH - 1);
  int b = bh >> 4;
  const u16* qr_ = qkv + ((size_t)(b * LL + l)) * QKS + h * KHD;
  const u16* kr_ = qr_ + 512;
  const float* kq = Kqk + d * KHD;
  const float* kk2 = Kqr + d * KHD;
  float sq = 0.f, sk = 0.f;
#pragma unroll
  for (int kk = 0; kk < KHD; ++kk) {
    sq += bf2f(qr_[kk]) * kq[kk];
    sk += bf2f(kr_[kk]) * kk2[kk];
  }
  qE2[idx] = sq;
  kEbf[(size_t)rest * 16 + d] = f2bf(sk * SCALEF + SCALEF * ekrs[d]);
}

// ---------------- attn A: batched loads (sched_barrier); chunk-major E ----------------
__global__ __launch_bounds__(256) void attn_exp_kernel(
    const u16* __restrict__ qkv, const float* __restrict__ qE2, const u16* __restrict__ kEbf,
    const unsigned char* __restrict__ didx, const float* __restrict__ Vsum,
    u16* __restrict__ E, float* __restrict__ vbias, float* __restrict__ invs) {
  const int i = blockIdx.x;
  const int j = i >> 3;
  const int g = (i & 7) * 8 + (j >> 5);
  const int qr = j & 31;
  const int h = g & 15, b = g >> 4;
  const int tid = threadIdx.x, lane = tid & 63, w = tid >> 6;
  const int lr = lane & 15, lg = lane >> 4;
  const int row0 = qr * 16;

  __shared__ u16 kEs[LL][18];
  __shared__ float qEs[16][17];
  __shared__ float hist[4][64][17];

  {
    const u32* gs = (const u32*)(kEbf + (((size_t)(b * HH + h)) * LL) * 16);
    u32* ls = (u32*)(&kEs[0][0]);
#pragma unroll
    for (int t = 0; t < 16; ++t) {
      int idx = t * 256 + tid;
      int r = idx >> 3, c = idx & 7;
      ls[r * 9 + c] = gs[idx];
    }
  }
  if (tid < 224) {
    int r = tid / 14, d = tid % 14;
    qEs[r][d] = qE2[(((size_t)(b * HH + h)) * LL + row0 + r) * NDB + d];
  }
  {
    float* hf = &hist[0][0][0];
#pragma unroll
    for (int t = 0; t < 17; ++t) hf[t * 256 + tid] = 0.f;
  }

  const bf16x8 aQ = *(const bf16x8*)(qkv + ((size_t)(b * LL + row0 + lr)) * QKS + h * KHD + lg * 8);

  __syncthreads();

  const f32x4 zero4 = {0.f, 0.f, 0.f, 0.f};
  const int keyA = 8 * (lr >> 2) + (lr & 3);
  const u16* kbase = qkv + (size_t)b * LL * QKS + 512 + h * KHD + lg * 8;
  const unsigned char* drow = didx + ((size_t)(b * LL) + row0 + lr) * LL + 8 * lg;
  u16* Ebh = E + (((size_t)(b * HH + h)) * 16) * (LL * 32) + (size_t)(row0 + lr) * 32 + 8 * lg;
  float* hlane = &hist[w][lane][0];

  bf16x8 kA[4], kB[4];
  uint2 dv[4];
#pragma unroll
  for (int ct = 0; ct < 4; ++ct) {
    const int x0 = w * 128 + ct * 32;
    kA[ct] = *(const bf16x8*)(kbase + (size_t)(x0 + keyA) * QKS);
    kB[ct] = *(const bf16x8*)(kbase + (size_t)(x0 + keyA + 4) * QKS);
    dv[ct] = *(const uint2*)(drow + x0);
  }
  __builtin_amdgcn_sched_barrier(0);

#pragma unroll
  for (int ct = 0; ct < 4; ++ct) {
    const int x0 = w * 128 + ct * 32;
    f32x4 sA = __builtin_amdgcn_mfma_f32_16x16x32_bf16(kA[ct], aQ, zero4, 0, 0, 0);
    f32x4 sB = __builtin_amdgcn_mfma_f32_16x16x32_bf16(kB[ct], aQ, zero4, 0, 0, 0);
    float pA[4], pB[4];
#pragma unroll
    for (int q = 0; q < 4; ++q) {
      const int da = (dv[ct].x >> (8 * q)) & 0xff;
      const int db = (dv[ct].y >> (8 * q)) & 0xff;
      pA[q] = __expf(sA[q] + qEs[lr][da] + bf2f(kEs[x0 + 8 * lg + q][da]));
      pB[q] = __expf(sB[q] + qEs[lr][db] + bf2f(kEs[x0 + 8 * lg + 4 + q][db]));
      hlane[da] += pA[q];
      hlane[db] += pB[q];
    }
    u32x4 pw;
    pw[0] = cvt_pk_bf16(pA[0], pA[1]);
    pw[1] = cvt_pk_bf16(pA[2], pA[3]);
    pw[2] = cvt_pk_bf16(pB[0], pB[1]);
    pw[3] = cvt_pk_bf16(pB[2], pB[3]);
    *(u32x4*)(Ebh + (size_t)(w * 4 + ct) * (LL * 32)) = pw;
  }

  __syncthreads();

  const int r = tid >> 4, c = tid & 15;
  float ht[NDB];
  float rsum = 0.f;
#pragma unroll
  for (int d = 0; d < NDB; ++d) {
    float a = 0.f;
#pragma unroll
    for (int ww = 0; ww < 4; ++ww)
#pragma unroll
      for (int gg = 0; gg < 4; ++gg) a += hist[ww][r + 16 * gg][d];
    ht[d] = a;
    rsum += a;
  }
  float vb_0 = 0.f, vb_1 = 0.f;
#pragma unroll
  for (int d = 0; d < NDB; ++d) {
    vb_0 += ht[d] * Vsum[d * KHD + c];
    vb_1 += ht[d] * Vsum[d * KHD + 16 + c];
  }
  const size_t rowi = (((size_t)(b * HH + h)) * LL) + row0 + r;
  vbias[rowi * KHD + c] = vb_0;
  vbias[rowi * KHD + 16 + c] = vb_1;
  if (c == 0) invs[rowi] = 1.0f / rsum;
}

// ---------------- attn B: z = (E @ V^T + vbias) * inv, chunk-major E ----------------
__global__ __launch_bounds__(256) void attn_pv_kernel(
    const u16* __restrict__ E, const u16* __restrict__ vtbf,
    const float* __restrict__ vbias, const float* __restrict__ invs,
    u16* __restrict__ z) {
  const int i = blockIdx.x;
  const int j = i >> 3;
  const int g = (i & 7) * 8 + (j >> 3);
  const int qt = j & 7;
  const int h = g & 15, b = g >> 4;
  const int tid = threadIdx.x, lane = tid & 63, w = tid >> 6;
  const int lr = lane & 15, lg = lane >> 4;
  const int row0 = qt * 64 + w * 16;

  f32x4 o0 = {0.f, 0.f, 0.f, 0.f}, o1 = {0.f, 0.f, 0.f, 0.f};
  const u16* Ebh = E + (((size_t)(b * HH + h)) * 16) * (LL * 32) + (size_t)(row0 + lr) * 32 + lg * 8;
  const u16* vbase = vtbf + ((size_t)(b * HH + h) * KHD) * LL + lg * 8;

#pragma unroll 4
  for (int ct = 0; ct < 16; ++ct) {
    const int x0 = ct * 32;
    bf16x8 aE = *(const bf16x8*)(Ebh + (size_t)ct * (LL * 32));
    bf16x8 vb0 = *(const bf16x8*)(vbase + (size_t)lr * LL + x0);
    bf16x8 vb1 = *(const bf16x8*)(vbase + (size_t)(16 + lr) * LL + x0);
    o0 = __builtin_amdgcn_mfma_f32_16x16x32_bf16(aE, vb0, o0, 0, 0, 0);
    o1 = __builtin_amdgcn_mfma_f32_16x16x32_bf16(aE, vb1, o1, 0, 0, 0);
  }

#pragma unroll
  for (int q = 0; q < 4; ++q) {
    const int rl = lg * 4 + q;
    const size_t rowi = (((size_t)(b * HH + h)) * LL) + row0 + rl;
    const float inv = invs[rowi];
    const float v0 = vbias[rowi * KHD + lr];
    const float v1 = vbias[rowi * KHD + 16 + lr];
    const size_t orow = ((size_t)(b * LL + row0 + rl)) * DDIM + h * KHD;
    z[orow + lr] = f2bf((o0[q] + v0) * inv);
    z[orow + 16 + lr] = f2bf((o1[q] + v1) * inv);
  }
}

// ---------------- out = LN(X + Y), f32 + bf16 ----------------
__global__ __launch_bounds__(256) void add_ln_kernel(
    const float* __restrict__ X, const float* __restrict__ Y,
    const float* __restrict__ g, const float* __restrict__ be,
    float* __restrict__ out, u16* __restrict__ outb) {
  const int row = blockIdx.x, tid = threadIdx.x;
  const int lane = tid & 63, wid = tid >> 6;
  __shared__ float red[4];
  const size_t base = (size_t)row * DDIM;
  float x0 = X[base + tid] + Y[base + tid];
  float x1 = X[base + tid + 256] + Y[base + tid + 256];
  float s = wredSum(x0 + x1);
  if (lane == 0) red[wid] = s;
  __syncthreads();
  float mu = (red[0] + red[1] + red[2] + red[3]) * (1.0f / DDIM);
  __syncthreads();
  float d0 = x0 - mu, d1 = x1 - mu;
  float vs = wredSum(d0 * d0 + d1 * d1);
  if (lane == 0) red[wid] = vs;
  __syncthreads();
  float var = (red[0] + red[1] + red[2] + red[3]) * (1.0f / DDIM);
  float inv = rsqrtf(var + 1e-5f);
  float r0 = d0 * inv * g[tid] + be[tid];
  float r1 = d1 * inv * g[tid + 256] + be[tid + 256];
  out[base + tid] = r0;
  out[base + tid + 256] = r1;
  outb[base + tid] = f2bf(r0);
  outb[base + tid + 256] = f2bf(r1);
}

// ---------------- pool v2 ----------------
__global__ __launch_bounds__(256) void pool2_kernel(const float* __restrict__ h, float* __restrict__ pooled) {
  const int s = blockIdx.x, b = blockIdx.y, tid = threadIdx.x;
  float a0 = 0.f, a1 = 0.f;
  const float* base = h + ((size_t)(b * LL) + s * 64) * DDIM;
#pragma unroll 4
  for (int l = 0; l < 64; ++l) {
    a0 += base[(size_t)l * DDIM + tid];
    a1 += base[(size_t)l * DDIM + tid + 256];
  }
  atomicAdd(&pooled[b * DDIM + tid], a0);
  atomicAdd(&pooled[b * DDIM + tid + 256], a1);
}

// ---------------- head stage 1 ----------------
__global__ __launch_bounds__(256) void head1_kernel(
    const float* __restrict__ pooled, const float* __restrict__ Wm1, float* __restrict__ hidden) {
  const int s = blockIdx.x, b = blockIdx.y, tid = threadIdx.x;
  __shared__ float pl[64];
  if (tid < 64) pl[tid] = pooled[b * DDIM + s * 64 + tid];
  __syncthreads();
  float a0 = 0.f, a1 = 0.f;
  const float* wbase = Wm1 + (size_t)(s * 64) * MMD;
#pragma unroll 8
  for (int dd = 0; dd < 64; ++dd) {
    float p = pl[dd];
    a0 += p * wbase[(size_t)dd * MMD + tid];
    a1 += p * wbase[(size_t)dd * MMD + tid + 256];
  }
  atomicAdd(&hidden[b * MMD + tid], a0);
  atomicAdd(&hidden[b * MMD + tid + 256], a1);
}

// ---------------- head stage 2 ----------------
__global__ __launch_bounds__(256) void head2_kernel(
    const float* __restrict__ hidden, const float* __restrict__ bm1,
    const float* __restrict__ Wm2, const float* __restrict__ bm2, float* __restrict__ out) {
  const int b = blockIdx.x, tid = threadIdx.x;
  float part = 0.f;
#pragma unroll
  for (int jj = 0; jj < 2; ++jj) {
    int j = tid + jj * 256;
    part += fmaxf(hidden[b * MMD + j] + bm1[j], 0.f) * Wm2[j];
  }
  __shared__ float red[4];
  int lane = tid & 63, wid = tid >> 6;
  float ssum = wredSum(part);
  if (lane == 0) red[wid] = ssum;
  __syncthreads();
  if (tid == 0) out[b] = red[0] + red[1] + red[2] + red[3] + bm2[0];
}

extern "C" void kernel_launch(void* const* d_in, const int* in_sizes, int n_in,
                              void* d_out, int out_size, void* d_ws, size_t ws_size,
                              hipStream_t stream) {
  const int* cell_types = (const int*)d_in[0];
  const float* distances = (const float*)d_in[1];
  const float* cell_emb = (const float*)d_in[2];
  const float* Kqk = (const float*)d_in[3];
  const float* Kqr = (const float*)d_in[4];
  const float* Kkr = (const float*)d_in[5];
  const float* Vqk = (const float*)d_in[6];
  const float* Vqr = (const float*)d_in[7];
  const float* Vkr = (const float*)d_in[8];
  const float* Wq = (const float*)d_in[9];
  const float* Wk = (const float*)d_in[10];
  const float* Wv = (const float*)d_in[11];
  const float* Wo = (const float*)d_in[12];
  const float* bq = (const float*)d_in[13];
  const float* bk = (const float*)d_in[14];
  const float* bv = (const float*)d_in[15];
  const float* bo = (const float*)d_in[16];
  const float* W1 = (const float*)d_in[17];
  const float* b1 = (const float*)d_in[18];
  const float* W2 = (const float*)d_in[19];
  const float* b2 = (const float*)d_in[20];
  const float* g1 = (const float*)d_in[21];
  const float* be1 = (const float*)d_in[22];
  const float* g2 = (const float*)d_in[23];
  const float* be2 = (const float*)d_in[24];
  const float* Wm1 = (const float*)d_in[25];
  const float* bm1 = (const float*)d_in[26];
  const float* Wm2 = (const float*)d_in[27];
  const float* bm2 = (const float*)d_in[28];

  char* w = (char*)d_ws;
  auto alloc = [&](size_t bytes) { void* p = (void*)w; w += (bytes + 255) & ~(size_t)255; return p; };
  unsigned char* didx = (unsigned char*)alloc(sizeof(unsigned char) * BB * LL * LL);
  float* h    = (float*)alloc(sizeof(float) * BB * LL * DDIM);
  u16* hbf    = (u16*)alloc(sizeof(u16) * BB * LL * DDIM);
  float* h2   = (float*)alloc(sizeof(float) * BB * LL * DDIM);
  u16* h2bf   = (u16*)alloc(sizeof(u16) * BB * LL * DDIM);
  u16* qkvbf  = (u16*)alloc(sizeof(u16) * BB * LL * QKS);
  float* ob   = (float*)alloc(sizeof(float) * BB * LL * DDIM);
  u16* f1bf   = (u16*)alloc(sizeof(u16) * BB * LL * FFD);
  u16* zbf    = (u16*)alloc(sizeof(u16) * BB * LL * DDIM);
  u16* vtbf   = (u16*)alloc(sizeof(u16) * BB * HH * KHD * LL);
  float* qE2  = (float*)alloc(sizeof(float) * BB * HH * LL * NDB);
  u16* kEbf   = (u16*)alloc(sizeof(u16) * (size_t)BB * HH * LL * 16);
  u16* Ebuf   = (u16*)alloc(sizeof(u16) * (size_t)BB * HH * LL * LL);
  float* vbias = (float*)alloc(sizeof(float) * (size_t)BB * HH * LL * KHD);
  float* invs = (float*)alloc(sizeof(float) * (size_t)BB * HH * LL);
  u16* Wqkvt  = (u16*)alloc(sizeof(u16) * (size_t)NLAY * QKS * DDIM);
  u16* Wot    = (u16*)alloc(sizeof(u16) * (size_t)NLAY * DDIM * DDIM);
  u16* W1t    = (u16*)alloc(sizeof(u16) * (size_t)NLAY * FFD * DDIM);
  u16* W2t    = (u16*)alloc(sizeof(u16) * (size_t)NLAY * DDIM * FFD);
  float* bqkv = (float*)alloc(sizeof(float) * NLAY * QKS);
  float* Vsum = (float*)alloc(sizeof(float) * NDB * KHD);
  float* EkrS = (float*)alloc(sizeof(float) * NDB);
  float* pooled = (float*)alloc(sizeof(float) * BB * DDIM);
  float* hidden = (float*)alloc(sizeof(float) * BB * MMD);

  const int Mrows = BB * LL;

  bucketize_kernel<<<(BB * LL * LL / 4 + 255) / 256, 256, 0, stream>>>(distances, didx, BB * LL * LL / 4);
  embed_kernel<<<(BB * LL * DDIM + 255) / 256, 256, 0, stream>>>(cell_types, cell_emb, h, hbf, BB * LL * DDIM);
  prep_kernel<<<1, 512, 0, stream>>>(Vqk, Vqr, Vkr, Kkr, Vsum, EkrS);
  biaspack_kernel<<<(NLAY * QKS + 255) / 256, 256, 0, stream>>>(bq, bk, bv, bqkv);
  hipMemsetAsync(pooled, 0, sizeof(float) * BB * DDIM, stream);
  hipMemsetAsync(hidden, 0, sizeof(float) * BB * MMD, stream);

  for (int lay = 0; lay < NLAY; ++lay) {
    wconv_layer<<<768, 256, 0, stream>>>(
        Wq + (size_t)lay * DDIM * DDIM, Wk + (size_t)lay * DDIM * DDIM,
        Wv + (size_t)lay * DDIM * DDIM, Wo + (size_t)lay * DDIM * DDIM,
        W1 + (size_t)lay * DDIM * FFD, W2 + (size_t)lay * FFD * DDIM,
        Wqkvt + (size_t)lay * QKS * DDIM, Wot + (size_t)lay * DDIM * DDIM,
        W1t + (size_t)lay * FFD * DDIM, W2t + (size_t)lay * DDIM * FFD);
  }

  const int nrel = BB * HH * LL * NDB;

  for (int lay = 0; lay < NLAY; ++lay) {
    // QKV on 64x64 tile: grid (2048/64)*(1536/64) = 768
    gemm64_bf16<0><<<dim3((Mrows / 64) * (QKS / 64)), 256, 0, stream>>>(
        hbf, Wqkvt + (size_t)lay * QKS * DDIM, bqkv + (size_t)lay * QKS,
        nullptr, qkvbf, vtbf, Mrows, QKS, DDIM);

    proj_qk_kernel<<<(nrel + 255) / 256, 256, 0, stream>>>(qkvbf, Kqk, Kqr, EkrS, qE2, kEbf);
    attn_exp_kernel<<<dim3(2048), 256, 0, stream>>>(qkvbf, qE2, kEbf, didx, Vsum, Ebuf, vbias, invs);
    attn_pv_kernel<<<dim3(512), 256, 0, stream>>>(Ebuf, vtbf, vbias, invs, zbf);

    gemm_bf16<1><<<dim3((Mrows / 32) * (DDIM / 64)), 256, 0, stream>>>(
        zbf, Wot + (size_t)lay * DDIM * DDIM, bo + (size_t)lay * DDIM, ob, nullptr, nullptr, Mrows, DDIM, DDIM);
    add_ln_kernel<<<Mrows, 256, 0, stream>>>(h, ob, g1 + (size_t)lay * DDIM, be1 + (size_t)lay * DDIM, h2, h2bf);
    // FF1 on 64x64 tile: grid (2048/64)*(2048/64) = 1024
    gemm64_bf16<2><<<dim3((Mrows / 64) * (FFD / 64)), 256, 0, stream>>>(
        h2bf, W1t + (size_t)lay * FFD * DDIM, b1 + (size_t)lay * FFD, nullptr, f1bf, nullptr, Mrows, FFD, DDIM);
    gemm_bf16<3><<<dim3((Mrows / 32) * (DDIM / 64)), 256, 0, stream>>>(
        f1bf, W2t + (size_t)lay * DDIM * FFD, b2 + (size_t)lay * DDIM, ob, nullptr, nullptr, Mrows, DDIM, FFD);
    add_ln_kernel<<<Mrows, 256, 0, stream>>>(h2, ob, g2 + (size_t)lay * DDIM, be2 + (size_t)lay * DDIM, h, hbf);
  }

  pool2_kernel<<<dim3(8, BB), 256, 0, stream>>>(h, pooled);
  head1_kernel<<<dim3(8, BB), 256, 0, stream>>>(pooled, Wm1, hidden);
  head2_kernel<<<BB, 256, 0, stream>>>(hidden, bm1, Wm2, bm2, (float*)d_out);
}

// Round 20
// 936.306 us; speedup vs baseline: 1.1864x; 1.0344x over previous
//
#include <hip/hip_runtime.h>
#include <math.h>

#define NLAY 8
#define BB 4
#define LL 512
#define DDIM 512
#define HH 16
#define KHD 32
#define FFD 2048
#define MMD 512
#define NDB 14
#define QKS 1536
#define SCALEF 0.17677669529663687f

typedef unsigned short u16;
typedef unsigned int u32;
typedef __attribute__((ext_vector_type(8))) short bf16x8;
typedef __attribute__((ext_vector_type(4))) float f32x4;
typedef __attribute__((ext_vector_type(4))) u32 u32x4;

__device__ __forceinline__ u16 f2bf(float f) {
  unsigned u = __builtin_bit_cast(unsigned, f);
  u = (u + 0x7fffu + ((u >> 16) & 1u)) >> 16;
  return (u16)u;
}
__device__ __forceinline__ float bf2f(u16 v) {
  unsigned u = ((unsigned)v) << 16;
  return __builtin_bit_cast(float, u);
}
__device__ __forceinline__ u32 cvt_pk_bf16(float lo, float hi) {
  u32 r;
  asm("v_cvt_pk_bf16_f32 %0, %1, %2" : "=v"(r) : "v"(lo), "v"(hi));
  return r;
}
__device__ __forceinline__ float wredSum(float v) {
#pragma unroll
  for (int o = 32; o > 0; o >>= 1) v += __shfl_down(v, o);
  return v;
}
__device__ __forceinline__ void gload_lds16(const u16* g, u16* l) {
  __builtin_amdgcn_global_load_lds((const __attribute__((address_space(1))) void*)g,
                                   (__attribute__((address_space(3))) void*)l, 16, 0, 0);
}

// ---------------- bucketize -> uint8, [b][l][x] layout ----------------
__global__ void bucketize_kernel(const float* __restrict__ dist, unsigned char* __restrict__ didx, int n) {
  int i = blockIdx.x * 256 + threadIdx.x;
  if (i >= n) return;
  float4 v = ((const float4*)dist)[i];
  float vv[4] = {v.x, v.y, v.z, v.w};
  unsigned char o[4];
#pragma unroll
  for (int j = 0; j < 4; ++j) {
    int c = 0;
#pragma unroll
    for (int s = 1; s <= NDB; ++s) c += (10.0f * (float)s < vv[j]) ? 1 : 0;
    o[j] = (unsigned char)(c > (NDB - 1) ? (NDB - 1) : c);
  }
  *(uchar4*)(didx + i * 4) = *(uchar4*)o;
}

// ---------------- h = cell_emb[cell_types] (f32 + bf16) ----------------
__global__ void embed_kernel(const int* __restrict__ ct, const float* __restrict__ emb,
                             float* __restrict__ h, u16* __restrict__ hbf, int n) {
  int i = blockIdx.x * 256 + threadIdx.x;
  if (i >= n) return;
  int bl = i >> 9, d = i & 511;
  float v = emb[ct[bl] * DDIM + d];
  h[i] = v;
  hbf[i] = f2bf(v);
}

// ---------------- Vsum, EkrS ----------------
__global__ void prep_kernel(const float* __restrict__ Vqk, const float* __restrict__ Vqr,
                            const float* __restrict__ Vkr, const float* __restrict__ Kkr,
                            float* __restrict__ Vsum, float* __restrict__ EkrS) {
  int tid = threadIdx.x;
  if (tid < NDB * KHD) Vsum[tid] = Vqk[tid] + Vqr[tid] + Vkr[tid];
  if (tid < NDB) {
    float s = 0.f;
    for (int kk = 0; kk < KHD; ++kk) s += Kkr[tid * KHD + kk];
    EkrS[tid] = s;
  }
}

// ---------------- packed qkv bias [NLAY][1536] ----------------
__global__ void biaspack_kernel(const float* __restrict__ bq, const float* __restrict__ bk,
                                const float* __restrict__ bv, float* __restrict__ bqkv) {
  int i = blockIdx.x * 256 + threadIdx.x;
  if (i >= NLAY * QKS) return;
  int lay = i / QKS, c = i % QKS;
  float v;
  if (c < 512) v = bq[lay * DDIM + c];
  else if (c < 1024) v = bk[lay * DDIM + c - 512];
  else v = bv[lay * DDIM + c - 1024];
  bqkv[i] = v;
}

// ---------------- weight transpose+convert ----------------
__device__ __forceinline__ void wtconv_tile(const float* __restrict__ src, u16* __restrict__ dst,
                                            int K, int N, int tn, int tk) {
  __shared__ float tl[64][65];
  const int t = threadIdx.x;
#pragma unroll
  for (int p = 0; p < 4; ++p) {
    int k = tk * 64 + p * 16 + (t >> 4);
    int n = tn * 64 + (t & 15) * 4;
    float4 v = *(const float4*)(src + (size_t)k * N + n);
    tl[(t & 15) * 4 + 0][p * 16 + (t >> 4)] = v.x;
    tl[(t & 15) * 4 + 1][p * 16 + (t >> 4)] = v.y;
    tl[(t & 15) * 4 + 2][p * 16 + (t >> 4)] = v.z;
    tl[(t & 15) * 4 + 3][p * 16 + (t >> 4)] = v.w;
  }
  __syncthreads();
  int n = t >> 2, cc = t & 3;
  u16 o[16];
#pragma unroll
  for (int e = 0; e < 16; ++e) o[e] = f2bf(tl[n][cc * 16 + e]);
  u16* dp = dst + (size_t)(tn * 64 + n) * K + tk * 64 + cc * 16;
  *(uint4*)(dp) = *(uint4*)&o[0];
  *(uint4*)(dp + 8) = *(uint4*)&o[8];
}

__global__ __launch_bounds__(256) void wconv_layer(
    const float* __restrict__ Wq, const float* __restrict__ Wk, const float* __restrict__ Wv,
    const float* __restrict__ Wo, const float* __restrict__ W1, const float* __restrict__ W2,
    u16* __restrict__ Wqkvt, u16* __restrict__ Wot, u16* __restrict__ W1t, u16* __restrict__ W2t) {
  int b = blockIdx.x;
  if (b < 64) { wtconv_tile(Wq, Wqkvt, 512, 512, b >> 3, b & 7); return; }
  if (b < 128) { b -= 64; wtconv_tile(Wk, Wqkvt + 512 * 512, 512, 512, b >> 3, b & 7); return; }
  if (b < 192) { b -= 128; wtconv_tile(Wv, Wqkvt + 1024 * 512, 512, 512, b >> 3, b & 7); return; }
  if (b < 256) { b -= 192; wtconv_tile(Wo, Wot, 512, 512, b >> 3, b & 7); return; }
  if (b < 512) { b -= 256; wtconv_tile(W1, W1t, 512, FFD, b >> 3, b & 7); return; }
  b -= 512; wtconv_tile(W2, W2t, FFD, 512, b >> 5, b & 31);
}

// ---------------- bf16 MFMA GEMM 32x64 (O=1, FF2=3) ----------------
template <int TAG>
__global__ __launch_bounds__(256) void gemm_bf16(
    const u16* __restrict__ A, const u16* __restrict__ Bt, const float* __restrict__ bias,
    float* __restrict__ Cf, u16* __restrict__ Cb, u16* __restrict__ Vt,
    int M, int N, int K) {
  __shared__ u16 As[32 * 64];
  __shared__ u16 Bs[64 * 64];
  const int tid = threadIdx.x, w = tid >> 6, lane = tid & 63;
  const int lr = lane & 15, lg = lane >> 4;
  const int wr = w >> 1, wc = w & 1;
  const int gx = N >> 6;
  const int bi = blockIdx.x;
  const int xcd = bi & 7, rr = bi >> 3;
  const int y = xcd * 8 + rr / gx, x = rr % gx;
  const int row0 = y * 32, col0 = x * 64;
  const int srow = lane >> 3;
  const int aoff = ((lane & 7) ^ srow) * 8;
  const f32x4 z4 = {0.f, 0.f, 0.f, 0.f};
  f32x4 acc[2] = {z4, z4};

  for (int k0 = 0; k0 < K; k0 += 64) {
    gload_lds16(A + (size_t)(row0 + w * 8 + srow) * K + k0 + aoff, As + (w * 8) * 64);
#pragma unroll
    for (int i = 0; i < 2; ++i)
      gload_lds16(Bt + (size_t)(col0 + w * 16 + i * 8 + srow) * K + k0 + aoff,
                  Bs + (w * 16 + i * 8) * 64);
    __syncthreads();
#pragma unroll
    for (int kh = 0; kh < 2; ++kh) {
      bf16x8 a, b[2];
      {
        int r = wr * 16 + lr;
        a = *(const bf16x8*)(As + r * 64 + (((kh * 4 + lg) ^ (r & 7)) << 3));
      }
#pragma unroll
      for (int ni = 0; ni < 2; ++ni) {
        int r = wc * 32 + ni * 16 + lr;
        b[ni] = *(const bf16x8*)(Bs + r * 64 + (((kh * 4 + lg) ^ (r & 7)) << 3));
      }
#pragma unroll
      for (int ni = 0; ni < 2; ++ni)
        acc[ni] = __builtin_amdgcn_mfma_f32_16x16x32_bf16(a, b[ni], acc[ni], 0, 0, 0);
    }
    __syncthreads();
  }
  {
    int r = row0 + wr * 16 + lg * 4;
#pragma unroll
    for (int ni = 0; ni < 2; ++ni) {
      int c = col0 + wc * 32 + ni * 16 + lr;
      float bs = bias[c];
#pragma unroll
      for (int j = 0; j < 4; ++j) {
        float v = acc[ni][j] + bs;
        size_t idx = (size_t)(r + j) * N + c;
        Cf[idx] = v;
      }
    }
  }
}

// ---------------- bf16 MFMA GEMM 64x64 (QKV=0, FF1=2) ----------------
template <int TAG>
__global__ __launch_bounds__(256) void gemm64_bf16(
    const u16* __restrict__ A, const u16* __restrict__ Bt, const float* __restrict__ bias,
    float* __restrict__ Cf, u16* __restrict__ Cb, u16* __restrict__ Vt,
    int M, int N, int K) {
  __shared__ u16 As[64 * 64];
  __shared__ u16 Bs[64 * 64];
  const int tid = threadIdx.x, w = tid >> 6, lane = tid & 63;
  const int lr = lane & 15, lg = lane >> 4;
  const int wr = w >> 1, wc = w & 1;
  const int gx = N >> 6;
  const int bi = blockIdx.x;
  const int xcd = bi & 7, rr = bi >> 3;
  const int ypx = M >> 9;
  const int y = xcd * ypx + rr / gx, x = rr % gx;
  const int row0 = y * 64, col0 = x * 64;
  const int srow = lane >> 3;
  const int aoff = ((lane & 7) ^ srow) * 8;
  const f32x4 z4 = {0.f, 0.f, 0.f, 0.f};
  f32x4 acc[2][2] = {{z4, z4}, {z4, z4}};

  for (int k0 = 0; k0 < K; k0 += 64) {
#pragma unroll
    for (int i = 0; i < 2; ++i) {
      gload_lds16(A + (size_t)(row0 + w * 16 + i * 8 + srow) * K + k0 + aoff,
                  As + (w * 16 + i * 8) * 64);
      gload_lds16(Bt + (size_t)(col0 + w * 16 + i * 8 + srow) * K + k0 + aoff,
                  Bs + (w * 16 + i * 8) * 64);
    }
    __syncthreads();
#pragma unroll
    for (int kh = 0; kh < 2; ++kh) {
      bf16x8 a[2], b[2];
#pragma unroll
      for (int mi = 0; mi < 2; ++mi) {
        int r = wr * 32 + mi * 16 + lr;
        a[mi] = *(const bf16x8*)(As + r * 64 + (((kh * 4 + lg) ^ (r & 7)) << 3));
      }
#pragma unroll
      for (int ni = 0; ni < 2; ++ni) {
        int r = wc * 32 + ni * 16 + lr;
        b[ni] = *(const bf16x8*)(Bs + r * 64 + (((kh * 4 + lg) ^ (r & 7)) << 3));
      }
#pragma unroll
      for (int mi = 0; mi < 2; ++mi)
#pragma unroll
        for (int ni = 0; ni < 2; ++ni)
          acc[mi][ni] = __builtin_amdgcn_mfma_f32_16x16x32_bf16(a[mi], b[ni], acc[mi][ni], 0, 0, 0);
    }
    __syncthreads();
  }
#pragma unroll
  for (int mi = 0; mi < 2; ++mi) {
    int r = row0 + wr * 32 + mi * 16 + lg * 4;
#pragma unroll
    for (int ni = 0; ni < 2; ++ni) {
      int c = col0 + wc * 32 + ni * 16 + lr;
      float bs = bias[c];
#pragma unroll
      for (int j = 0; j < 4; ++j) {
        float v = acc[mi][ni][j] + bs;
        int rg = r + j;
        size_t idx = (size_t)rg * N + c;
        if (TAG == 0) {
          if (c < 1024) {
            Cb[idx] = f2bf(c < 512 ? v * SCALEF : v);
          } else {
            int cc = c - 1024, hh = cc >> 5, kh2 = cc & 31;
            int bb = rg >> 9, l = rg & 511;
            Vt[(((size_t)(bb * HH + hh)) * KHD + kh2) * LL + l] = f2bf(v);
          }
        } else {
          v = 0.5f * v * (1.0f + erff(v * 0.70710678118654752f));
          Cb[idx] = f2bf(v);
        }
      }
    }
  }
}

// ---------------- merged rel projections: qE2 (f32) + kEbf (bf16 [bhl][16]) ----------------
__global__ void proj_qk_kernel(const u16* __restrict__ qkv, const float* __restrict__ Kqk,
                               const float* __restrict__ Kqr, const float* __restrict__ ekrs,
                               float* __restrict__ qE2, u16* __restrict__ kEbf) {
  int idx = blockIdx.x * 256 + threadIdx.x;
  if (idx >= BB * HH * LL * NDB) return;
  int d = idx % NDB;
  int rest = idx / NDB;
  int l = rest & (LL - 1);
  int bh = rest >> 9;
  int h = bh & (HH - 1);
  int b = bh >> 4;
  const u16* qr_ = qkv + ((size_t)(b * LL + l)) * QKS + h * KHD;
  const u16* kr_ = qr_ + 512;
  const float* kq = Kqk + d * KHD;
  const float* kk2 = Kqr + d * KHD;
  float sq = 0.f, sk = 0.f;
#pragma unroll
  for (int kk = 0; kk < KHD; ++kk) {
    sq += bf2f(qr_[kk]) * kq[kk];
    sk += bf2f(kr_[kk]) * kk2[kk];
  }
  qE2[idx] = sq;
  kEbf[(size_t)rest * 16 + d] = f2bf(sk * SCALEF + SCALEF * ekrs[d]);
}

// ---------------- attn A: batched loads; chunk-major E; two-stage epilogue fold (guard FIXED) ----------------
__global__ __launch_bounds__(256) void attn_exp_kernel(
    const u16* __restrict__ qkv, const float* __restrict__ qE2, const u16* __restrict__ kEbf,
    const unsigned char* __restrict__ didx, const float* __restrict__ Vsum,
    u16* __restrict__ E, float* __restrict__ vbias, float* __restrict__ invs) {
  const int i = blockIdx.x;
  const int j = i >> 3;
  const int g = (i & 7) * 8 + (j >> 5);
  const int qr = j & 31;
  const int h = g & 15, b = g >> 4;
  const int tid = threadIdx.x, lane = tid & 63, w = tid >> 6;
  const int lr = lane & 15, lg = lane >> 4;
  const int row0 = qr * 16;

  __shared__ u16 kEs[LL][18];
  __shared__ float qEs[16][17];
  __shared__ float hist[4 * 64 * 17];

  {
    const u32* gs = (const u32*)(kEbf + (((size_t)(b * HH + h)) * LL) * 16);
    u32* ls = (u32*)(&kEs[0][0]);
#pragma unroll
    for (int t = 0; t < 16; ++t) {
      int idx = t * 256 + tid;
      int r = idx >> 3, c = idx & 7;
      ls[r * 9 + c] = gs[idx];
    }
  }
  if (tid < 224) {
    int r = tid / 14, d = tid % 14;
    qEs[r][d] = qE2[(((size_t)(b * HH + h)) * LL + row0 + r) * NDB + d];
  }
#pragma unroll
  for (int t = 0; t < 17; ++t) hist[t * 256 + tid] = 0.f;

  const bf16x8 aQ = *(const bf16x8*)(qkv + ((size_t)(b * LL + row0 + lr)) * QKS + h * KHD + lg * 8);

  __syncthreads();

  const f32x4 zero4 = {0.f, 0.f, 0.f, 0.f};
  const int keyA = 8 * (lr >> 2) + (lr & 3);
  const u16* kbase = qkv + (size_t)b * LL * QKS + 512 + h * KHD + lg * 8;
  const unsigned char* drow = didx + ((size_t)(b * LL) + row0 + lr) * LL + 8 * lg;
  u16* Ebh = E + (((size_t)(b * HH + h)) * 16) * (LL * 32) + (size_t)(row0 + lr) * 32 + 8 * lg;
  float* hlane = &hist[(size_t)(w * 64 + lane) * 17];

  bf16x8 kA[4], kB[4];
  uint2 dv[4];
#pragma unroll
  for (int ct = 0; ct < 4; ++ct) {
    const int x0 = w * 128 + ct * 32;
    kA[ct] = *(const bf16x8*)(kbase + (size_t)(x0 + keyA) * QKS);
    kB[ct] = *(const bf16x8*)(kbase + (size_t)(x0 + keyA + 4) * QKS);
    dv[ct] = *(const uint2*)(drow + x0);
  }
  __builtin_amdgcn_sched_barrier(0);

#pragma unroll
  for (int ct = 0; ct < 4; ++ct) {
    const int x0 = w * 128 + ct * 32;
    f32x4 sA = __builtin_amdgcn_mfma_f32_16x16x32_bf16(kA[ct], aQ, zero4, 0, 0, 0);
    f32x4 sB = __builtin_amdgcn_mfma_f32_16x16x32_bf16(kB[ct], aQ, zero4, 0, 0, 0);
    float pA[4], pB[4];
#pragma unroll
    for (int q = 0; q < 4; ++q) {
      const int da = (dv[ct].x >> (8 * q)) & 0xff;
      const int db = (dv[ct].y >> (8 * q)) & 0xff;
      pA[q] = __expf(sA[q] + qEs[lr][da] + bf2f(kEs[x0 + 8 * lg + q][da]));
      pB[q] = __expf(sB[q] + qEs[lr][db] + bf2f(kEs[x0 + 8 * lg + 4 + q][db]));
      hlane[da] += pA[q];
      hlane[db] += pB[q];
    }
    u32x4 pw;
    pw[0] = cvt_pk_bf16(pA[0], pA[1]);
    pw[1] = cvt_pk_bf16(pA[2], pA[3]);
    pw[2] = cvt_pk_bf16(pB[0], pB[1]);
    pw[3] = cvt_pk_bf16(pB[2], pB[3]);
    *(u32x4*)(Ebh + (size_t)(w * 4 + ct) * (LL * 32)) = pw;
  }

  __syncthreads();

  // ---- stage 1: fold wave-copies (1088 slots across 256 threads)
#pragma unroll
  for (int t = 0; t < 5; ++t) {
    int s = t * 256 + tid;
    if (s < 1088) {
      hist[s] = hist[s] + hist[1088 + s] + hist[2176 + s] + hist[3264 + s];
    }
  }
  __syncthreads();
  // ---- stage 2: fold row-copies (272 slots; FIXED: two passes since 272 > 256)
#pragma unroll
  for (int t = 0; t < 2; ++t) {
    int s = t * 256 + tid;
    if (s < 272) {
      int r = s / 17, d = s % 17;
      hist[r * 17 + d] = hist[r * 17 + d] + hist[(r + 16) * 17 + d] +
                         hist[(r + 32) * 17 + d] + hist[(r + 48) * 17 + d];
    }
  }
  __syncthreads();

  // ---- final: thread (r,c): 14 broadcast reads
  const int r = tid >> 4, c = tid & 15;
  float ht[NDB];
  float rsum = 0.f;
#pragma unroll
  for (int d = 0; d < NDB; ++d) {
    float a = hist[r * 17 + d];
    ht[d] = a;
    rsum += a;
  }
  float vb_0 = 0.f, vb_1 = 0.f;
#pragma unroll
  for (int d = 0; d < NDB; ++d) {
    vb_0 += ht[d] * Vsum[d * KHD + c];
    vb_1 += ht[d] * Vsum[d * KHD + 16 + c];
  }
  const size_t rowi = (((size_t)(b * HH + h)) * LL) + row0 + r;
  vbias[rowi * KHD + c] = vb_0;
  vbias[rowi * KHD + 16 + c] = vb_1;
  if (c == 0) invs[rowi] = 1.0f / rsum;
}

// ---------------- attn B: z = (E @ V^T + vbias) * inv, chunk-major E ----------------
__global__ __launch_bounds__(256) void attn_pv_kernel(
    const u16* __restrict__ E, const u16* __restrict__ vtbf,
    const float* __restrict__ vbias, const float* __restrict__ invs,
    u16* __restrict__ z) {
  const int i = blockIdx.x;
  const int j = i >> 3;
  const int g = (i & 7) * 8 + (j >> 3);
  const int qt = j & 7;
  const int h = g & 15, b = g >> 4;
  const int tid = threadIdx.x, lane = tid & 63, w = tid >> 6;
  const int lr = lane & 15, lg = lane >> 4;
  const int row0 = qt * 64 + w * 16;

  f32x4 o0 = {0.f, 0.f, 0.f, 0.f}, o1 = {0.f, 0.f, 0.f, 0.f};
  const u16* Ebh = E + (((size_t)(b * HH + h)) * 16) * (LL * 32) + (size_t)(row0 + lr) * 32 + lg * 8;
  const u16* vbase = vtbf + ((size_t)(b * HH + h) * KHD) * LL + lg * 8;

#pragma unroll 4
  for (int ct = 0; ct < 16; ++ct) {
    const int x0 = ct * 32;
    bf16x8 aE = *(const bf16x8*)(Ebh + (size_t)ct * (LL * 32));
    bf16x8 vb0 = *(const bf16x8*)(vbase + (size_t)lr * LL + x0);
    bf16x8 vb1 = *(const bf16x8*)(vbase + (size_t)(16 + lr) * LL + x0);
    o0 = __builtin_amdgcn_mfma_f32_16x16x32_bf16(aE, vb0, o0, 0, 0, 0);
    o1 = __builtin_amdgcn_mfma_f32_16x16x32_bf16(aE, vb1, o1, 0, 0, 0);
  }

#pragma unroll
  for (int q = 0; q < 4; ++q) {
    const int rl = lg * 4 + q;
    const size_t rowi = (((size_t)(b * HH + h)) * LL) + row0 + rl;
    const float inv = invs[rowi];
    const float v0 = vbias[rowi * KHD + lr];
    const float v1 = vbias[rowi * KHD + 16 + lr];
    const size_t orow = ((size_t)(b * LL + row0 + rl)) * DDIM + h * KHD;
    z[orow + lr] = f2bf((o0[q] + v0) * inv);
    z[orow + 16 + lr] = f2bf((o1[q] + v1) * inv);
  }
}

// ---------------- out = LN(X + Y), f32 + bf16 ----------------
__global__ __launch_bounds__(256) void add_ln_kernel(
    const float* __restrict__ X, const float* __restrict__ Y,
    const float* __restrict__ g, const float* __restrict__ be,
    float* __restrict__ out, u16* __restrict__ outb) {
  const int row = blockIdx.x, tid = threadIdx.x;
  const int lane = tid & 63, wid = tid >> 6;
  __shared__ float red[4];
  const size_t base = (size_t)row * DDIM;
  float x0 = X[base + tid] + Y[base + tid];
  float x1 = X[base + tid + 256] + Y[base + tid + 256];
  float s = wredSum(x0 + x1);
  if (lane == 0) red[wid] = s;
  __syncthreads();
  float mu = (red[0] + red[1] + red[2] + red[3]) * (1.0f / DDIM);
  __syncthreads();
  float d0 = x0 - mu, d1 = x1 - mu;
  float vs = wredSum(d0 * d0 + d1 * d1);
  if (lane == 0) red[wid] = vs;
  __syncthreads();
  float var = (red[0] + red[1] + red[2] + red[3]) * (1.0f / DDIM);
  float inv = rsqrtf(var + 1e-5f);
  float r0 = d0 * inv * g[tid] + be[tid];
  float r1 = d1 * inv * g[tid + 256] + be[tid + 256];
  out[base + tid] = r0;
  out[base + tid + 256] = r1;
  outb[base + tid] = f2bf(r0);
  outb[base + tid + 256] = f2bf(r1);
}

// ---------------- pool v2 ----------------
__global__ __launch_bounds__(256) void pool2_kernel(const float* __restrict__ h, float* __restrict__ pooled) {
  const int s = blockIdx.x, b = blockIdx.y, tid = threadIdx.x;
  float a0 = 0.f, a1 = 0.f;
  const float* base = h + ((size_t)(b * LL) + s * 64) * DDIM;
#pragma unroll 4
  for (int l = 0; l < 64; ++l) {
    a0 += base[(size_t)l * DDIM + tid];
    a1 += base[(size_t)l * DDIM + tid + 256];
  }
  atomicAdd(&pooled[b * DDIM + tid], a0);
  atomicAdd(&pooled[b * DDIM + tid + 256], a1);
}

// ---------------- head stage 1 ----------------
__global__ __launch_bounds__(256) void head1_kernel(
    const float* __restrict__ pooled, const float* __restrict__ Wm1, float* __restrict__ hidden) {
  const int s = blockIdx.x, b = blockIdx.y, tid = threadIdx.x;
  __shared__ float pl[64];
  if (tid < 64) pl[tid] = pooled[b * DDIM + s * 64 + tid];
  __syncthreads();
  float a0 = 0.f, a1 = 0.f;
  const float* wbase = Wm1 + (size_t)(s * 64) * MMD;
#pragma unroll 8
  for (int dd = 0; dd < 64; ++dd) {
    float p = pl[dd];
    a0 += p * wbase[(size_t)dd * MMD + tid];
    a1 += p * wbase[(size_t)dd * MMD + tid + 256];
  }
  atomicAdd(&hidden[b * MMD + tid], a0);
  atomicAdd(&hidden[b * MMD + tid + 256], a1);
}

// ---------------- head stage 2 ----------------
__global__ __launch_bounds__(256) void head2_kernel(
    const float* __restrict__ hidden, const float* __restrict__ bm1,
    const float* __restrict__ Wm2, const float* __restrict__ bm2, float* __restrict__ out) {
  const int b = blockIdx.x, tid = threadIdx.x;
  float part = 0.f;
#pragma unroll
  for (int jj = 0; jj < 2; ++jj) {
    int j = tid + jj * 256;
    part += fmaxf(hidden[b * MMD + j] + bm1[j], 0.f) * Wm2[j];
  }
  __shared__ float red[4];
  int lane = tid & 63, wid = tid >> 6;
  float ssum = wredSum(part);
  if (lane == 0) red[wid] = ssum;
  __syncthreads();
  if (tid == 0) out[b] = red[0] + red[1] + red[2] + red[3] + bm2[0];
}

extern "C" void kernel_launch(void* const* d_in, const int* in_sizes, int n_in,
                              void* d_out, int out_size, void* d_ws, size_t ws_size,
                              hipStream_t stream) {
  const int* cell_types = (const int*)d_in[0];
  const float* distances = (const float*)d_in[1];
  const float* cell_emb = (const float*)d_in[2];
  const float* Kqk = (const float*)d_in[3];
  const float* Kqr = (const float*)d_in[4];
  const float* Kkr = (const float*)d_in[5];
  const float* Vqk = (const float*)d_in[6];
  const float* Vqr = (const float*)d_in[7];
  const float* Vkr = (const float*)d_in[8];
  const float* Wq = (const float*)d_in[9];
  const float* Wk = (const float*)d_in[10];
  const float* Wv = (const float*)d_in[11];
  const float* Wo = (const float*)d_in[12];
  const float* bq = (const float*)d_in[13];
  const float* bk = (const float*)d_in[14];
  const float* bv = (const float*)d_in[15];
  const float* bo = (const float*)d_in[16];
  const float* W1 = (const float*)d_in[17];
  const float* b1 = (const float*)d_in[18];
  const float* W2 = (const float*)d_in[19];
  const float* b2 = (const float*)d_in[20];
  const float* g1 = (const float*)d_in[21];
  const float* be1 = (const float*)d_in[22];
  const float* g2 = (const float*)d_in[23];
  const float* be2 = (const float*)d_in[24];
  const float* Wm1 = (const float*)d_in[25];
  const float* bm1 = (const float*)d_in[26];
  const float* Wm2 = (const float*)d_in[27];
  const float* bm2 = (const float*)d_in[28];

  char* w = (char*)d_ws;
  auto alloc = [&](size_t bytes) { void* p = (void*)w; w += (bytes + 255) & ~(size_t)255; return p; };
  unsigned char* didx = (unsigned char*)alloc(sizeof(unsigned char) * BB * LL * LL);
  float* h    = (float*)alloc(sizeof(float) * BB * LL * DDIM);
  u16* hbf    = (u16*)alloc(sizeof(u16) * BB * LL * DDIM);
  float* h2   = (float*)alloc(sizeof(float) * BB * LL * DDIM);
  u16* h2bf   = (u16*)alloc(sizeof(u16) * BB * LL * DDIM);
  u16* qkvbf  = (u16*)alloc(sizeof(u16) * BB * LL * QKS);
  float* ob   = (float*)alloc(sizeof(float) * BB * LL * DDIM);
  u16* f1bf   = (u16*)alloc(sizeof(u16) * BB * LL * FFD);
  u16* zbf    = (u16*)alloc(sizeof(u16) * BB * LL * DDIM);
  u16* vtbf   = (u16*)alloc(sizeof(u16) * BB * HH * KHD * LL);
  float* qE2  = (float*)alloc(sizeof(float) * BB * HH * LL * NDB);
  u16* kEbf   = (u16*)alloc(sizeof(u16) * (size_t)BB * HH * LL * 16);
  u16* Ebuf   = (u16*)alloc(sizeof(u16) * (size_t)BB * HH * LL * LL);
  float* vbias = (float*)alloc(sizeof(float) * (size_t)BB * HH * LL * KHD);
  float* invs = (float*)alloc(sizeof(float) * (size_t)BB * HH * LL);
  u16* Wqkvt  = (u16*)alloc(sizeof(u16) * (size_t)NLAY * QKS * DDIM);
  u16* Wot    = (u16*)alloc(sizeof(u16) * (size_t)NLAY * DDIM * DDIM);
  u16* W1t    = (u16*)alloc(sizeof(u16) * (size_t)NLAY * FFD * DDIM);
  u16* W2t    = (u16*)alloc(sizeof(u16) * (size_t)NLAY * DDIM * FFD);
  float* bqkv = (float*)alloc(sizeof(float) * NLAY * QKS);
  float* Vsum = (float*)alloc(sizeof(float) * NDB * KHD);
  float* EkrS = (float*)alloc(sizeof(float) * NDB);
  float* pooled = (float*)alloc(sizeof(float) * BB * DDIM);
  float* hidden = (float*)alloc(sizeof(float) * BB * MMD);

  const int Mrows = BB * LL;

  bucketize_kernel<<<(BB * LL * LL / 4 + 255) / 256, 256, 0, stream>>>(distances, didx, BB * LL * LL / 4);
  embed_kernel<<<(BB * LL * DDIM + 255) / 256, 256, 0, stream>>>(cell_types, cell_emb, h, hbf, BB * LL * DDIM);
  prep_kernel<<<1, 512, 0, stream>>>(Vqk, Vqr, Vkr, Kkr, Vsum, EkrS);
  biaspack_kernel<<<(NLAY * QKS + 255) / 256, 256, 0, stream>>>(bq, bk, bv, bqkv);
  hipMemsetAsync(pooled, 0, sizeof(float) * BB * DDIM, stream);
  hipMemsetAsync(hidden, 0, sizeof(float) * BB * MMD, stream);

  for (int lay = 0; lay < NLAY; ++lay) {
    wconv_layer<<<768, 256, 0, stream>>>(
        Wq + (size_t)lay * DDIM * DDIM, Wk + (size_t)lay * DDIM * DDIM,
        Wv + (size_t)lay * DDIM * DDIM, Wo + (size_t)lay * DDIM * DDIM,
        W1 + (size_t)lay * DDIM * FFD, W2 + (size_t)lay * FFD * DDIM,
        Wqkvt + (size_t)lay * QKS * DDIM, Wot + (size_t)lay * DDIM * DDIM,
        W1t + (size_t)lay * FFD * DDIM, W2t + (size_t)lay * DDIM * FFD);
  }

  const int nrel = BB * HH * LL * NDB;

  for (int lay = 0; lay < NLAY; ++lay) {
    gemm64_bf16<0><<<dim3((Mrows / 64) * (QKS / 64)), 256, 0, stream>>>(
        hbf, Wqkvt + (size_t)lay * QKS * DDIM, bqkv + (size_t)lay * QKS,
        nullptr, qkvbf, vtbf, Mrows, QKS, DDIM);

    proj_qk_kernel<<<(nrel + 255) / 256, 256, 0, stream>>>(qkvbf, Kqk, Kqr, EkrS, qE2, kEbf);
    attn_exp_kernel<<<dim3(2048), 256, 0, stream>>>(qkvbf, qE2, kEbf, didx, Vsum, Ebuf, vbias, invs);
    attn_pv_kernel<<<dim3(512), 256, 0, stream>>>(Ebuf, vtbf, vbias, invs, zbf);

    gemm_bf16<1><<<dim3((Mrows / 32) * (DDIM / 64)), 256, 0, stream>>>(
        zbf, Wot + (size_t)lay * DDIM * DDIM, bo + (size_t)lay * DDIM, ob, nullptr, nullptr, Mrows, DDIM, DDIM);
    add_ln_kernel<<<Mrows, 256, 0, stream>>>(h, ob, g1 + (size_t)lay * DDIM, be1 + (size_t)lay * DDIM, h2, h2bf);
    gemm64_bf16<2><<<dim3((Mrows / 64) * (FFD / 64)), 256, 0, stream>>>(
        h2bf, W1t + (size_t)lay * FFD * DDIM, b1 + (size_t)lay * FFD, nullptr, f1bf, nullptr, Mrows, FFD, DDIM);
    gemm_bf16<3><<<dim3((Mrows / 32) * (DDIM / 64)), 256, 0, stream>>>(
        f1bf, W2t + (size_t)lay * DDIM * FFD, b2 + (size_t)lay * DDIM, ob, nullptr, nullptr, Mrows, DDIM, FFD);
    add_ln_kernel<<<Mrows, 256, 0, stream>>>(h2, ob, g2 + (size_t)lay * DDIM, be2 + (size_t)lay * DDIM, h, hbf);
  }

  pool2_kernel<<<dim3(8, BB), 256, 0, stream>>>(h, pooled);
  head1_kernel<<<dim3(8, BB), 256, 0, stream>>>(pooled, Wm1, hidden);
  head2_kernel<<<BB, 256, 0, stream>>>(hidden, bm1, Wm2, bm2, (float*)d_out);
}

// Round 22
// 887.656 us; speedup vs baseline: 1.2514x; 1.0548x over previous
//
#include <hip/hip_runtime.h>
#include <math.h>

#define NLAY 8
#define BB 4
#define LL 512
#define DDIM 512
#define HH 16
#define KHD 32
#define FFD 2048
#define MMD 512
#define NDB 14
#define QKS 1536
#define SCALEF 0.17677669529663687f

typedef unsigned short u16;
typedef unsigned int u32;
typedef __attribute__((ext_vector_type(8))) short bf16x8;
typedef __attribute__((ext_vector_type(4))) float f32x4;
typedef __attribute__((ext_vector_type(4))) u32 u32x4;

__device__ __forceinline__ u16 f2bf(float f) {
  unsigned u = __builtin_bit_cast(unsigned, f);
  u = (u + 0x7fffu + ((u >> 16) & 1u)) >> 16;
  return (u16)u;
}
__device__ __forceinline__ float bf2f(u16 v) {
  unsigned u = ((unsigned)v) << 16;
  return __builtin_bit_cast(float, u);
}
__device__ __forceinline__ u32 cvt_pk_bf16(float lo, float hi) {
  u32 r;
  asm("v_cvt_pk_bf16_f32 %0, %1, %2" : "=v"(r) : "v"(lo), "v"(hi));
  return r;
}
__device__ __forceinline__ float wredSum(float v) {
#pragma unroll
  for (int o = 32; o > 0; o >>= 1) v += __shfl_down(v, o);
  return v;
}
__device__ __forceinline__ void gload_lds16(const u16* g, u16* l) {
  __builtin_amdgcn_global_load_lds((const __attribute__((address_space(1))) void*)g,
                                   (__attribute__((address_space(3))) void*)l, 16, 0, 0);
}

// ---------------- bucketize -> uint8, [b][l][x] layout ----------------
__global__ void bucketize_kernel(const float* __restrict__ dist, unsigned char* __restrict__ didx, int n) {
  int i = blockIdx.x * 256 + threadIdx.x;
  if (i >= n) return;
  float4 v = ((const float4*)dist)[i];
  float vv[4] = {v.x, v.y, v.z, v.w};
  unsigned char o[4];
#pragma unroll
  for (int j = 0; j < 4; ++j) {
    int c = 0;
#pragma unroll
    for (int s = 1; s <= NDB; ++s) c += (10.0f * (float)s < vv[j]) ? 1 : 0;
    o[j] = (unsigned char)(c > (NDB - 1) ? (NDB - 1) : c);
  }
  *(uchar4*)(didx + i * 4) = *(uchar4*)o;
}

// ---------------- h = cell_emb[cell_types] (f32 + bf16) ----------------
__global__ void embed_kernel(const int* __restrict__ ct, const float* __restrict__ emb,
                             float* __restrict__ h, u16* __restrict__ hbf, int n) {
  int i = blockIdx.x * 256 + threadIdx.x;
  if (i >= n) return;
  int bl = i >> 9, d = i & 511;
  float v = emb[ct[bl] * DDIM + d];
  h[i] = v;
  hbf[i] = f2bf(v);
}

// ---------------- Vsum, EkrS ----------------
__global__ void prep_kernel(const float* __restrict__ Vqk, const float* __restrict__ Vqr,
                            const float* __restrict__ Vkr, const float* __restrict__ Kkr,
                            float* __restrict__ Vsum, float* __restrict__ EkrS) {
  int tid = threadIdx.x;
  if (tid < NDB * KHD) Vsum[tid] = Vqk[tid] + Vqr[tid] + Vkr[tid];
  if (tid < NDB) {
    float s = 0.f;
    for (int kk = 0; kk < KHD; ++kk) s += Kkr[tid * KHD + kk];
    EkrS[tid] = s;
  }
}

// ---------------- packed qkv bias [NLAY][1536] ----------------
__global__ void biaspack_kernel(const float* __restrict__ bq, const float* __restrict__ bk,
                                const float* __restrict__ bv, float* __restrict__ bqkv) {
  int i = blockIdx.x * 256 + threadIdx.x;
  if (i >= NLAY * QKS) return;
  int lay = i / QKS, c = i % QKS;
  float v;
  if (c < 512) v = bq[lay * DDIM + c];
  else if (c < 1024) v = bk[lay * DDIM + c - 512];
  else v = bv[lay * DDIM + c - 1024];
  bqkv[i] = v;
}

// ---------------- weight transpose+convert ----------------
__device__ __forceinline__ void wtconv_tile(const float* __restrict__ src, u16* __restrict__ dst,
                                            int K, int N, int tn, int tk) {
  __shared__ float tl[64][65];
  const int t = threadIdx.x;
#pragma unroll
  for (int p = 0; p < 4; ++p) {
    int k = tk * 64 + p * 16 + (t >> 4);
    int n = tn * 64 + (t & 15) * 4;
    float4 v = *(const float4*)(src + (size_t)k * N + n);
    tl[(t & 15) * 4 + 0][p * 16 + (t >> 4)] = v.x;
    tl[(t & 15) * 4 + 1][p * 16 + (t >> 4)] = v.y;
    tl[(t & 15) * 4 + 2][p * 16 + (t >> 4)] = v.z;
    tl[(t & 15) * 4 + 3][p * 16 + (t >> 4)] = v.w;
  }
  __syncthreads();
  int n = t >> 2, cc = t & 3;
  u16 o[16];
#pragma unroll
  for (int e = 0; e < 16; ++e) o[e] = f2bf(tl[n][cc * 16 + e]);
  u16* dp = dst + (size_t)(tn * 64 + n) * K + tk * 64 + cc * 16;
  *(uint4*)(dp) = *(uint4*)&o[0];
  *(uint4*)(dp + 8) = *(uint4*)&o[8];
}

__global__ __launch_bounds__(256) void wconv_layer(
    const float* __restrict__ Wq, const float* __restrict__ Wk, const float* __restrict__ Wv,
    const float* __restrict__ Wo, const float* __restrict__ W1, const float* __restrict__ W2,
    u16* __restrict__ Wqkvt, u16* __restrict__ Wot, u16* __restrict__ W1t, u16* __restrict__ W2t) {
  int b = blockIdx.x;
  if (b < 64) { wtconv_tile(Wq, Wqkvt, 512, 512, b >> 3, b & 7); return; }
  if (b < 128) { b -= 64; wtconv_tile(Wk, Wqkvt + 512 * 512, 512, 512, b >> 3, b & 7); return; }
  if (b < 192) { b -= 128; wtconv_tile(Wv, Wqkvt + 1024 * 512, 512, 512, b >> 3, b & 7); return; }
  if (b < 256) { b -= 192; wtconv_tile(Wo, Wot, 512, 512, b >> 3, b & 7); return; }
  if (b < 512) { b -= 256; wtconv_tile(W1, W1t, 512, FFD, b >> 3, b & 7); return; }
  b -= 512; wtconv_tile(W2, W2t, FFD, 512, b >> 5, b & 31);
}

// ---------------- bf16 MFMA GEMM 32x64 (O=1, FF2=3) ----------------
template <int TAG>
__global__ __launch_bounds__(256) void gemm_bf16(
    const u16* __restrict__ A, const u16* __restrict__ Bt, const float* __restrict__ bias,
    float* __restrict__ Cf, u16* __restrict__ Cb, u16* __restrict__ Vt,
    int M, int N, int K) {
  __shared__ u16 As[32 * 64];
  __shared__ u16 Bs[64 * 64];
  const int tid = threadIdx.x, w = tid >> 6, lane = tid & 63;
  const int lr = lane & 15, lg = lane >> 4;
  const int wr = w >> 1, wc = w & 1;
  const int gx = N >> 6;
  const int bi = blockIdx.x;
  const int xcd = bi & 7, rr = bi >> 3;
  const int y = xcd * 8 + rr / gx, x = rr % gx;
  const int row0 = y * 32, col0 = x * 64;
  const int srow = lane >> 3;
  const int aoff = ((lane & 7) ^ srow) * 8;
  const f32x4 z4 = {0.f, 0.f, 0.f, 0.f};
  f32x4 acc[2] = {z4, z4};

  for (int k0 = 0; k0 < K; k0 += 64) {
    gload_lds16(A + (size_t)(row0 + w * 8 + srow) * K + k0 + aoff, As + (w * 8) * 64);
#pragma unroll
    for (int i = 0; i < 2; ++i)
      gload_lds16(Bt + (size_t)(col0 + w * 16 + i * 8 + srow) * K + k0 + aoff,
                  Bs + (w * 16 + i * 8) * 64);
    __syncthreads();
#pragma unroll
    for (int kh = 0; kh < 2; ++kh) {
      bf16x8 a, b[2];
      {
        int r = wr * 16 + lr;
        a = *(const bf16x8*)(As + r * 64 + (((kh * 4 + lg) ^ (r & 7)) << 3));
      }
#pragma unroll
      for (int ni = 0; ni < 2; ++ni) {
        int r = wc * 32 + ni * 16 + lr;
        b[ni] = *(const bf16x8*)(Bs + r * 64 + (((kh * 4 + lg) ^ (r & 7)) << 3));
      }
#pragma unroll
      for (int ni = 0; ni < 2; ++ni)
        acc[ni] = __builtin_amdgcn_mfma_f32_16x16x32_bf16(a, b[ni], acc[ni], 0, 0, 0);
    }
    __syncthreads();
  }
  {
    int r = row0 + wr * 16 + lg * 4;
#pragma unroll
    for (int ni = 0; ni < 2; ++ni) {
      int c = col0 + wc * 32 + ni * 16 + lr;
      float bs = bias[c];
#pragma unroll
      for (int j = 0; j < 4; ++j) {
        float v = acc[ni][j] + bs;
        size_t idx = (size_t)(r + j) * N + c;
        Cf[idx] = v;
      }
    }
  }
}

// ---------------- bf16 MFMA GEMM 64x64 (QKV=0, FF1=2) ----------------
template <int TAG>
__global__ __launch_bounds__(256) void gemm64_bf16(
    const u16* __restrict__ A, const u16* __restrict__ Bt, const float* __restrict__ bias,
    float* __restrict__ Cf, u16* __restrict__ Cb, u16* __restrict__ Vt,
    int M, int N, int K) {
  __shared__ u16 As[64 * 64];
  __shared__ u16 Bs[64 * 64];
  const int tid = threadIdx.x, w = tid >> 6, lane = tid & 63;
  const int lr = lane & 15, lg = lane >> 4;
  const int wr = w >> 1, wc = w & 1;
  const int gx = N >> 6;
  const int bi = blockIdx.x;
  const int xcd = bi & 7, rr = bi >> 3;
  const int ypx = M >> 9;
  const int y = xcd * ypx + rr / gx, x = rr % gx;
  const int row0 = y * 64, col0 = x * 64;
  const int srow = lane >> 3;
  const int aoff = ((lane & 7) ^ srow) * 8;
  const f32x4 z4 = {0.f, 0.f, 0.f, 0.f};
  f32x4 acc[2][2] = {{z4, z4}, {z4, z4}};

  for (int k0 = 0; k0 < K; k0 += 64) {
#pragma unroll
    for (int i = 0; i < 2; ++i) {
      gload_lds16(A + (size_t)(row0 + w * 16 + i * 8 + srow) * K + k0 + aoff,
                  As + (w * 16 + i * 8) * 64);
      gload_lds16(Bt + (size_t)(col0 + w * 16 + i * 8 + srow) * K + k0 + aoff,
                  Bs + (w * 16 + i * 8) * 64);
    }
    __syncthreads();
#pragma unroll
    for (int kh = 0; kh < 2; ++kh) {
      bf16x8 a[2], b[2];
#pragma unroll
      for (int mi = 0; mi < 2; ++mi) {
        int r = wr * 32 + mi * 16 + lr;
        a[mi] = *(const bf16x8*)(As + r * 64 + (((kh * 4 + lg) ^ (r & 7)) << 3));
      }
#pragma unroll
      for (int ni = 0; ni < 2; ++ni) {
        int r = wc * 32 + ni * 16 + lr;
        b[ni] = *(const bf16x8*)(Bs + r * 64 + (((kh * 4 + lg) ^ (r & 7)) << 3));
      }
#pragma unroll
      for (int mi = 0; mi < 2; ++mi)
#pragma unroll
        for (int ni = 0; ni < 2; ++ni)
          acc[mi][ni] = __builtin_amdgcn_mfma_f32_16x16x32_bf16(a[mi], b[ni], acc[mi][ni], 0, 0, 0);
    }
    __syncthreads();
  }
#pragma unroll
  for (int mi = 0; mi < 2; ++mi) {
    int r = row0 + wr * 32 + mi * 16 + lg * 4;
#pragma unroll
    for (int ni = 0; ni < 2; ++ni) {
      int c = col0 + wc * 32 + ni * 16 + lr;
      float bs = bias[c];
#pragma unroll
      for (int j = 0; j < 4; ++j) {
        float v = acc[mi][ni][j] + bs;
        int rg = r + j;
        size_t idx = (size_t)rg * N + c;
        if (TAG == 0) {
          if (c < 1024) {
            Cb[idx] = f2bf(c < 512 ? v * SCALEF : v);
          } else {
            int cc = c - 1024, hh = cc >> 5, kh2 = cc & 31;
            int bb = rg >> 9, l = rg & 511;
            Vt[(((size_t)(bb * HH + hh)) * KHD + kh2) * LL + l] = f2bf(v);
          }
        } else {
          v = 0.5f * v * (1.0f + erff(v * 0.70710678118654752f));
          Cb[idx] = f2bf(v);
        }
      }
    }
  }
}

// ---------------- proj_qk v2: one thread per (b,h,l); Kr staged in LDS (448 slots, 2 passes) ----------------
__global__ __launch_bounds__(256) void proj_qk2_kernel(
    const u16* __restrict__ qkv, const float* __restrict__ Kqk,
    const float* __restrict__ Kqr, const float* __restrict__ ekrs,
    float* __restrict__ qE2, u16* __restrict__ kEbf) {
  __shared__ float kqs[NDB * KHD];   // 448 floats
  __shared__ float kks[NDB * KHD];
  __shared__ float eks[NDB];
  const int tid = threadIdx.x;
#pragma unroll
  for (int t = 0; t < 2; ++t) {      // FIXED: 448 > 256, stage in two passes
    int s = t * 256 + tid;
    if (s < NDB * KHD) {
      kqs[s] = Kqk[s];
      kks[s] = Kqr[s];
    }
  }
  if (tid < NDB) eks[tid] = SCALEF * ekrs[tid];
  __syncthreads();

  const int idx = blockIdx.x * 256 + tid;   // (b*16+h)*512 + l, 32768 total
  const int l = idx & 511;
  const int bh = idx >> 9;
  const int hh = bh & 15, b = bh >> 4;
  const u16* qp = qkv + ((size_t)(b * LL + l)) * QKS + hh * KHD;
  float qv[KHD], kv[KHD];
#pragma unroll
  for (int t = 0; t < 4; ++t) {
    bf16x8 qx = *(const bf16x8*)(qp + t * 8);
    bf16x8 kx = *(const bf16x8*)(qp + 512 + t * 8);
#pragma unroll
    for (int e = 0; e < 8; ++e) {
      qv[t * 8 + e] = bf2f((u16)qx[e]);
      kv[t * 8 + e] = bf2f((u16)kx[e]);
    }
  }
  float oq[NDB];
  u16 ok[16];
#pragma unroll
  for (int d = 0; d < NDB; ++d) {
    float sq = 0.f, sk = 0.f;
#pragma unroll
    for (int kk = 0; kk < KHD; ++kk) {
      sq += qv[kk] * kqs[d * KHD + kk];
      sk += kv[kk] * kks[d * KHD + kk];
    }
    oq[d] = sq;                              // q pre-scaled by SCALEF in QKV epilogue
    ok[d] = f2bf(sk * SCALEF + eks[d]);
  }
  ok[14] = 0; ok[15] = 0;
  float* qo = qE2 + (size_t)idx * NDB;
#pragma unroll
  for (int d = 0; d < NDB; ++d) qo[d] = oq[d];
  *(uint4*)(kEbf + (size_t)idx * 16) = *(uint4*)&ok[0];
  *(uint4*)(kEbf + (size_t)idx * 16 + 8) = *(uint4*)&ok[8];
}

// ---------------- attn A: batched loads; chunk-major E; two-stage epilogue fold ----------------
__global__ __launch_bounds__(256) void attn_exp_kernel(
    const u16* __restrict__ qkv, const float* __restrict__ qE2, const u16* __restrict__ kEbf,
    const unsigned char* __restrict__ didx, const float* __restrict__ Vsum,
    u16* __restrict__ E, float* __restrict__ vbias, float* __restrict__ invs) {
  const int i = blockIdx.x;
  const int j = i >> 3;
  const int g = (i & 7) * 8 + (j >> 5);
  const int qr = j & 31;
  const int h = g & 15, b = g >> 4;
  const int tid = threadIdx.x, lane = tid & 63, w = tid >> 6;
  const int lr = lane & 15, lg = lane >> 4;
  const int row0 = qr * 16;

  __shared__ u16 kEs[LL][18];
  __shared__ float qEs[16][17];
  __shared__ float hist[4 * 64 * 17];

  {
    const u32* gs = (const u32*)(kEbf + (((size_t)(b * HH + h)) * LL) * 16);
    u32* ls = (u32*)(&kEs[0][0]);
#pragma unroll
    for (int t = 0; t < 16; ++t) {
      int idx = t * 256 + tid;
      int r = idx >> 3, c = idx & 7;
      ls[r * 9 + c] = gs[idx];
    }
  }
  if (tid < 224) {
    int r = tid / 14, d = tid % 14;
    qEs[r][d] = qE2[(((size_t)(b * HH + h)) * LL + row0 + r) * NDB + d];
  }
#pragma unroll
  for (int t = 0; t < 17; ++t) hist[t * 256 + tid] = 0.f;

  const bf16x8 aQ = *(const bf16x8*)(qkv + ((size_t)(b * LL + row0 + lr)) * QKS + h * KHD + lg * 8);

  __syncthreads();

  const f32x4 zero4 = {0.f, 0.f, 0.f, 0.f};
  const int keyA = 8 * (lr >> 2) + (lr & 3);
  const u16* kbase = qkv + (size_t)b * LL * QKS + 512 + h * KHD + lg * 8;
  const unsigned char* drow = didx + ((size_t)(b * LL) + row0 + lr) * LL + 8 * lg;
  u16* Ebh = E + (((size_t)(b * HH + h)) * 16) * (LL * 32) + (size_t)(row0 + lr) * 32 + 8 * lg;
  float* hlane = &hist[(size_t)(w * 64 + lane) * 17];

  bf16x8 kA[4], kB[4];
  uint2 dv[4];
#pragma unroll
  for (int ct = 0; ct < 4; ++ct) {
    const int x0 = w * 128 + ct * 32;
    kA[ct] = *(const bf16x8*)(kbase + (size_t)(x0 + keyA) * QKS);
    kB[ct] = *(const bf16x8*)(kbase + (size_t)(x0 + keyA + 4) * QKS);
    dv[ct] = *(const uint2*)(drow + x0);
  }
  __builtin_amdgcn_sched_barrier(0);

#pragma unroll
  for (int ct = 0; ct < 4; ++ct) {
    const int x0 = w * 128 + ct * 32;
    f32x4 sA = __builtin_amdgcn_mfma_f32_16x16x32_bf16(kA[ct], aQ, zero4, 0, 0, 0);
    f32x4 sB = __builtin_amdgcn_mfma_f32_16x16x32_bf16(kB[ct], aQ, zero4, 0, 0, 0);
    float pA[4], pB[4];
#pragma unroll
    for (int q = 0; q < 4; ++q) {
      const int da = (dv[ct].x >> (8 * q)) & 0xff;
      const int db = (dv[ct].y >> (8 * q)) & 0xff;
      pA[q] = __expf(sA[q] + qEs[lr][da] + bf2f(kEs[x0 + 8 * lg + q][da]));
      pB[q] = __expf(sB[q] + qEs[lr][db] + bf2f(kEs[x0 + 8 * lg + 4 + q][db]));
      hlane[da] += pA[q];
      hlane[db] += pB[q];
    }
    u32x4 pw;
    pw[0] = cvt_pk_bf16(pA[0], pA[1]);
    pw[1] = cvt_pk_bf16(pA[2], pA[3]);
    pw[2] = cvt_pk_bf16(pB[0], pB[1]);
    pw[3] = cvt_pk_bf16(pB[2], pB[3]);
    *(u32x4*)(Ebh + (size_t)(w * 4 + ct) * (LL * 32)) = pw;
  }

  __syncthreads();

#pragma unroll
  for (int t = 0; t < 5; ++t) {
    int s = t * 256 + tid;
    if (s < 1088) {
      hist[s] = hist[s] + hist[1088 + s] + hist[2176 + s] + hist[3264 + s];
    }
  }
  __syncthreads();
#pragma unroll
  for (int t = 0; t < 2; ++t) {
    int s = t * 256 + tid;
    if (s < 272) {
      int r = s / 17, d = s % 17;
      hist[r * 17 + d] = hist[r * 17 + d] + hist[(r + 16) * 17 + d] +
                         hist[(r + 32) * 17 + d] + hist[(r + 48) * 17 + d];
    }
  }
  __syncthreads();

  const int r = tid >> 4, c = tid & 15;
  float ht[NDB];
  float rsum = 0.f;
#pragma unroll
  for (int d = 0; d < NDB; ++d) {
    float a = hist[r * 17 + d];
    ht[d] = a;
    rsum += a;
  }
  float vb_0 = 0.f, vb_1 = 0.f;
#pragma unroll
  for (int d = 0; d < NDB; ++d) {
    vb_0 += ht[d] * Vsum[d * KHD + c];
    vb_1 += ht[d] * Vsum[d * KHD + 16 + c];
  }
  const size_t rowi = (((size_t)(b * HH + h)) * LL) + row0 + r;
  vbias[rowi * KHD + c] = vb_0;
  vbias[rowi * KHD + 16 + c] = vb_1;
  if (c == 0) invs[rowi] = 1.0f / rsum;
}

// ---------------- attn B: z = (E @ V^T + vbias) * inv, chunk-major E ----------------
__global__ __launch_bounds__(256) void attn_pv_kernel(
    const u16* __restrict__ E, const u16* __restrict__ vtbf,
    const float* __restrict__ vbias, const float* __restrict__ invs,
    u16* __restrict__ z) {
  const int i = blockIdx.x;
  const int j = i >> 3;
  const int g = (i & 7) * 8 + (j >> 3);
  const int qt = j & 7;
  const int h = g & 15, b = g >> 4;
  const int tid = threadIdx.x, lane = tid & 63, w = tid >> 6;
  const int lr = lane & 15, lg = lane >> 4;
  const int row0 = qt * 64 + w * 16;

  f32x4 o0 = {0.f, 0.f, 0.f, 0.f}, o1 = {0.f, 0.f, 0.f, 0.f};
  const u16* Ebh = E + (((size_t)(b * HH + h)) * 16) * (LL * 32) + (size_t)(row0 + lr) * 32 + lg * 8;
  const u16* vbase = vtbf + ((size_t)(b * HH + h) * KHD) * LL + lg * 8;

#pragma unroll 4
  for (int ct = 0; ct < 16; ++ct) {
    const int x0 = ct * 32;
    bf16x8 aE = *(const bf16x8*)(Ebh + (size_t)ct * (LL * 32));
    bf16x8 vb0 = *(const bf16x8*)(vbase + (size_t)lr * LL + x0);
    bf16x8 vb1 = *(const bf16x8*)(vbase + (size_t)(16 + lr) * LL + x0);
    o0 = __builtin_amdgcn_mfma_f32_16x16x32_bf16(aE, vb0, o0, 0, 0, 0);
    o1 = __builtin_amdgcn_mfma_f32_16x16x32_bf16(aE, vb1, o1, 0, 0, 0);
  }

#pragma unroll
  for (int q = 0; q < 4; ++q) {
    const int rl = lg * 4 + q;
    const size_t rowi = (((size_t)(b * HH + h)) * LL) + row0 + rl;
    const float inv = invs[rowi];
    const float v0 = vbias[rowi * KHD + lr];
    const float v1 = vbias[rowi * KHD + 16 + lr];
    const size_t orow = ((size_t)(b * LL + row0 + rl)) * DDIM + h * KHD;
    z[orow + lr] = f2bf((o0[q] + v0) * inv);
    z[orow + 16 + lr] = f2bf((o1[q] + v1) * inv);
  }
}

// ---------------- out = LN(X + Y), f32 + bf16 ----------------
__global__ __launch_bounds__(256) void add_ln_kernel(
    const float* __restrict__ X, const float* __restrict__ Y,
    const float* __restrict__ g, const float* __restrict__ be,
    float* __restrict__ out, u16* __restrict__ outb) {
  const int row = blockIdx.x, tid = threadIdx.x;
  const int lane = tid & 63, wid = tid >> 6;
  __shared__ float red[4];
  const size_t base = (size_t)row * DDIM;
  float x0 = X[base + tid] + Y[base + tid];
  float x1 = X[base + tid + 256] + Y[base + tid + 256];
  float s = wredSum(x0 + x1);
  if (lane == 0) red[wid] = s;
  __syncthreads();
  float mu = (red[0] + red[1] + red[2] + red[3]) * (1.0f / DDIM);
  __syncthreads();
  float d0 = x0 - mu, d1 = x1 - mu;
  float vs = wredSum(d0 * d0 + d1 * d1);
  if (lane == 0) red[wid] = vs;
  __syncthreads();
  float var = (red[0] + red[1] + red[2] + red[3]) * (1.0f / DDIM);
  float inv = rsqrtf(var + 1e-5f);
  float r0 = d0 * inv * g[tid] + be[tid];
  float r1 = d1 * inv * g[tid + 256] + be[tid + 256];
  out[base + tid] = r0;
  out[base + tid + 256] = r1;
  outb[base + tid] = f2bf(r0);
  outb[base + tid + 256] = f2bf(r1);
}

// ---------------- pool v2 ----------------
__global__ __launch_bounds__(256) void pool2_kernel(const float* __restrict__ h, float* __restrict__ pooled) {
  const int s = blockIdx.x, b = blockIdx.y, tid = threadIdx.x;
  float a0 = 0.f, a1 = 0.f;
  const float* base = h + ((size_t)(b * LL) + s * 64) * DDIM;
#pragma unroll 4
  for (int l = 0; l < 64; ++l) {
    a0 += base[(size_t)l * DDIM + tid];
    a1 += base[(size_t)l * DDIM + tid + 256];
  }
  atomicAdd(&pooled[b * DDIM + tid], a0);
  atomicAdd(&pooled[b * DDIM + tid + 256], a1);
}

// ---------------- head stage 1 ----------------
__global__ __launch_bounds__(256) void head1_kernel(
    const float* __restrict__ pooled, const float* __restrict__ Wm1, float* __restrict__ hidden) {
  const int s = blockIdx.x, b = blockIdx.y, tid = threadIdx.x;
  __shared__ float pl[64];
  if (tid < 64) pl[tid] = pooled[b * DDIM + s * 64 + tid];
  __syncthreads();
  float a0 = 0.f, a1 = 0.f;
  const float* wbase = Wm1 + (size_t)(s * 64) * MMD;
#pragma unroll 8
  for (int dd = 0; dd < 64; ++dd) {
    float p = pl[dd];
    a0 += p * wbase[(size_t)dd * MMD + tid];
    a1 += p * wbase[(size_t)dd * MMD + tid + 256];
  }
  atomicAdd(&hidden[b * MMD + tid], a0);
  atomicAdd(&hidden[b * MMD + tid + 256], a1);
}

// ---------------- head stage 2 ----------------
__global__ __launch_bounds__(256) void head2_kernel(
    const float* __restrict__ hidden, const float* __restrict__ bm1,
    const float* __restrict__ Wm2, const float* __restrict__ bm2, float* __restrict__ out) {
  const int b = blockIdx.x, tid = threadIdx.x;
  float part = 0.f;
#pragma unroll
  for (int jj = 0; jj < 2; ++jj) {
    int j = tid + jj * 256;
    part += fmaxf(hidden[b * MMD + j] + bm1[j], 0.f) * Wm2[j];
  }
  __shared__ float red[4];
  int lane = tid & 63, wid = tid >> 6;
  float ssum = wredSum(part);
  if (lane == 0) red[wid] = ssum;
  __syncthreads();
  if (tid == 0) out[b] = red[0] + red[1] + red[2] + red[3] + bm2[0];
}

extern "C" void kernel_launch(void* const* d_in, const int* in_sizes, int n_in,
                              void* d_out, int out_size, void* d_ws, size_t ws_size,
                              hipStream_t stream) {
  const int* cell_types = (const int*)d_in[0];
  const float* distances = (const float*)d_in[1];
  const float* cell_emb = (const float*)d_in[2];
  const float* Kqk = (const float*)d_in[3];
  const float* Kqr = (const float*)d_in[4];
  const float* Kkr = (const float*)d_in[5];
  const float* Vqk = (const float*)d_in[6];
  const float* Vqr = (const float*)d_in[7];
  const float* Vkr = (const float*)d_in[8];
  const float* Wq = (const float*)d_in[9];
  const float* Wk = (const float*)d_in[10];
  const float* Wv = (const float*)d_in[11];
  const float* Wo = (const float*)d_in[12];
  const float* bq = (const float*)d_in[13];
  const float* bk = (const float*)d_in[14];
  const float* bv = (const float*)d_in[15];
  const float* bo = (const float*)d_in[16];
  const float* W1 = (const float*)d_in[17];
  const float* b1 = (const float*)d_in[18];
  const float* W2 = (const float*)d_in[19];
  const float* b2 = (const float*)d_in[20];
  const float* g1 = (const float*)d_in[21];
  const float* be1 = (const float*)d_in[22];
  const float* g2 = (const float*)d_in[23];
  const float* be2 = (const float*)d_in[24];
  const float* Wm1 = (const float*)d_in[25];
  const float* bm1 = (const float*)d_in[26];
  const float* Wm2 = (const float*)d_in[27];
  const float* bm2 = (const float*)d_in[28];

  char* w = (char*)d_ws;
  auto alloc = [&](size_t bytes) { void* p = (void*)w; w += (bytes + 255) & ~(size_t)255; return p; };
  unsigned char* didx = (unsigned char*)alloc(sizeof(unsigned char) * BB * LL * LL);
  float* h    = (float*)alloc(sizeof(float) * BB * LL * DDIM);
  u16* hbf    = (u16*)alloc(sizeof(u16) * BB * LL * DDIM);
  float* h2   = (float*)alloc(sizeof(float) * BB * LL * DDIM);
  u16* h2bf   = (u16*)alloc(sizeof(u16) * BB * LL * DDIM);
  u16* qkvbf  = (u16*)alloc(sizeof(u16) * BB * LL * QKS);
  float* ob   = (float*)alloc(sizeof(float) * BB * LL * DDIM);
  u16* f1bf   = (u16*)alloc(sizeof(u16) * BB * LL * FFD);
  u16* zbf    = (u16*)alloc(sizeof(u16) * BB * LL * DDIM);
  u16* vtbf   = (u16*)alloc(sizeof(u16) * BB * HH * KHD * LL);
  float* qE2  = (float*)alloc(sizeof(float) * BB * HH * LL * NDB);
  u16* kEbf   = (u16*)alloc(sizeof(u16) * (size_t)BB * HH * LL * 16);
  u16* Ebuf   = (u16*)alloc(sizeof(u16) * (size_t)BB * HH * LL * LL);
  float* vbias = (float*)alloc(sizeof(float) * (size_t)BB * HH * LL * KHD);
  float* invs = (float*)alloc(sizeof(float) * (size_t)BB * HH * LL);
  u16* Wqkvt  = (u16*)alloc(sizeof(u16) * (size_t)NLAY * QKS * DDIM);
  u16* Wot    = (u16*)alloc(sizeof(u16) * (size_t)NLAY * DDIM * DDIM);
  u16* W1t    = (u16*)alloc(sizeof(u16) * (size_t)NLAY * FFD * DDIM);
  u16* W2t    = (u16*)alloc(sizeof(u16) * (size_t)NLAY * DDIM * FFD);
  float* bqkv = (float*)alloc(sizeof(float) * NLAY * QKS);
  float* Vsum = (float*)alloc(sizeof(float) * NDB * KHD);
  float* EkrS = (float*)alloc(sizeof(float) * NDB);
  float* pooled = (float*)alloc(sizeof(float) * BB * DDIM);
  float* hidden = (float*)alloc(sizeof(float) * BB * MMD);

  const int Mrows = BB * LL;

  bucketize_kernel<<<(BB * LL * LL / 4 + 255) / 256, 256, 0, stream>>>(distances, didx, BB * LL * LL / 4);
  embed_kernel<<<(BB * LL * DDIM + 255) / 256, 256, 0, stream>>>(cell_types, cell_emb, h, hbf, BB * LL * DDIM);
  prep_kernel<<<1, 512, 0, stream>>>(Vqk, Vqr, Vkr, Kkr, Vsum, EkrS);
  biaspack_kernel<<<(NLAY * QKS + 255) / 256, 256, 0, stream>>>(bq, bk, bv, bqkv);
  hipMemsetAsync(pooled, 0, sizeof(float) * BB * DDIM, stream);
  hipMemsetAsync(hidden, 0, sizeof(float) * BB * MMD, stream);

  for (int lay = 0; lay < NLAY; ++lay) {
    wconv_layer<<<768, 256, 0, stream>>>(
        Wq + (size_t)lay * DDIM * DDIM, Wk + (size_t)lay * DDIM * DDIM,
        Wv + (size_t)lay * DDIM * DDIM, Wo + (size_t)lay * DDIM * DDIM,
        W1 + (size_t)lay * DDIM * FFD, W2 + (size_t)lay * FFD * DDIM,
        Wqkvt + (size_t)lay * QKS * DDIM, Wot + (size_t)lay * DDIM * DDIM,
        W1t + (size_t)lay * FFD * DDIM, W2t + (size_t)lay * DDIM * FFD);
  }

  for (int lay = 0; lay < NLAY; ++lay) {
    gemm64_bf16<0><<<dim3((Mrows / 64) * (QKS / 64)), 256, 0, stream>>>(
        hbf, Wqkvt + (size_t)lay * QKS * DDIM, bqkv + (size_t)lay * QKS,
        nullptr, qkvbf, vtbf, Mrows, QKS, DDIM);

    proj_qk2_kernel<<<dim3(BB * HH * LL / 256), 256, 0, stream>>>(qkvbf, Kqk, Kqr, EkrS, qE2, kEbf);
    attn_exp_kernel<<<dim3(2048), 256, 0, stream>>>(qkvbf, qE2, kEbf, didx, Vsum, Ebuf, vbias, invs);
    attn_pv_kernel<<<dim3(512), 256, 0, stream>>>(Ebuf, vtbf, vbias, invs, zbf);

    gemm_bf16<1><<<dim3((Mrows / 32) * (DDIM / 64)), 256, 0, stream>>>(
        zbf, Wot + (size_t)lay * DDIM * DDIM, bo + (size_t)lay * DDIM, ob, nullptr, nullptr, Mrows, DDIM, DDIM);
    add_ln_kernel<<<Mrows, 256, 0, stream>>>(h, ob, g1 + (size_t)lay * DDIM, be1 + (size_t)lay * DDIM, h2, h2bf);
    gemm64_bf16<2><<<dim3((Mrows / 64) * (FFD / 64)), 256, 0, stream>>>(
        h2bf, W1t + (size_t)lay * FFD * DDIM, b1 + (size_t)lay * FFD, nullptr, f1bf, nullptr, Mrows, FFD, DDIM);
    gemm_bf16<3><<<dim3((Mrows / 32) * (DDIM / 64)), 256, 0, stream>>>(
        f1bf, W2t + (size_t)lay * DDIM * FFD, b2 + (size_t)lay * DDIM, ob, nullptr, nullptr, Mrows, DDIM, FFD);
    add_ln_kernel<<<Mrows, 256, 0, stream>>>(h2, ob, g2 + (size_t)lay * DDIM, be2 + (size_t)lay * DDIM, h, hbf);
  }

  pool2_kernel<<<dim3(8, BB), 256, 0, stream>>>(h, pooled);
  head1_kernel<<<dim3(8, BB), 256, 0, stream>>>(pooled, Wm1, hidden);
  head2_kernel<<<BB, 256, 0, stream>>>(hidden, bm1, Wm2, bm2, (float*)d_out);
}